// Round 13
// baseline (2343.933 us; speedup 1.0000x reference)
//
#include <hip/hip_runtime.h>

#define HID 256

typedef unsigned short u16;
typedef __attribute__((ext_vector_type(8))) short bf16x8;
typedef __attribute__((ext_vector_type(4))) float f32x4;

__device__ __forceinline__ float siluf(float x) { return x / (1.f + __expf(-x)); }
// tanh-approx gelu via sigmoid identity: 0.5x(1+tanh(z)) == x*sigmoid(2z)
__device__ __forceinline__ float geluf(float x) {
    return x / (1.f + __expf(-(1.59576912f * x + 0.07135481f * x * x * x)));
}
__device__ __forceinline__ u16 f2b(float x) {
    unsigned u = __float_as_uint(x);
    unsigned r = u + 0x7FFFu + ((u >> 16) & 1u);
    return (u16)(r >> 16);
}
__device__ __forceinline__ float b2f(u16 h) {
    return __uint_as_float(((unsigned)h) << 16);
}
__device__ __forceinline__ void gload16(const u16* g, u16* l) {
    __builtin_amdgcn_global_load_lds(
        (const __attribute__((address_space(1))) unsigned int*)g,
        (__attribute__((address_space(3))) unsigned int*)l, 16, 0, 0);
}
__device__ __forceinline__ int imin(int a, int b) { return a < b ? a : b; }

// ---------------- bf16 MFMA GEMM: C = act(A @ Bt^T + bias) ------------------------------
// A: M x K bf16 (lda). Bt: N x K bf16 (ldb). 64x128 tile, BK=32, 4 waves 2x2 of 32x64.
// 2-phase double-buffered staging (2 x 12KB); repack reuses lds[0..8191] (16KB).
// act: 1=silu, 2=gelu, 4=gelu on global cols [0,256) only. N%128==0, K%32==0.
__global__ __launch_bounds__(256) void gemm_mfma(
    const u16* __restrict__ A, int lda,
    const u16* __restrict__ Bt, int ldb,
    void* __restrict__ Cv, int ldc,
    int M, int N, int K,
    const float* __restrict__ bias, int act, int obf16)
{
    __shared__ u16 lds[12288];   // 2 x (A[64][32] + B[128][32]) = 2 x 6144 u16

    const int tid  = threadIdx.x;
    const int lane = tid & 63;
    const int wave = tid >> 6;
    const int row0 = blockIdx.y * 64;
    const int col0 = blockIdx.x * 128;
    const int wm   = (wave >> 1) * 32;
    const int wn   = (wave & 1) * 64;

    f32x4 acc[2][4];
#pragma unroll
    for (int i = 0; i < 2; ++i)
#pragma unroll
        for (int j = 0; j < 4; ++j) acc[i][j] = (f32x4)0.0f;

    const int kc = (lane & 3) * 8;
    const int rr  = wave * 16 + (lane >> 2);
    const int rb1 = (wave + 4) * 16 + (lane >> 2);
    const u16* pa  = A + (size_t)imin(row0 + rr, M - 1) * lda + kc;
    const u16* pb0 = Bt + (size_t)(col0 + rr) * ldb + kc;
    const u16* pb1 = Bt + (size_t)(col0 + rb1) * ldb + kc;

    const int kb = (lane >> 4) * 8;
    const int fr = lane & 15;

    auto stage = [&](int buf, int k0) {
        u16* base = &lds[buf * 6144];
        gload16(pa + k0, base + wave * 512);
        gload16(pb0 + k0, base + 2048 + wave * 512);
        gload16(pb1 + k0, base + 2048 + (wave + 4) * 512);
    };

    stage(0, 0);
    __syncthreads();
    int cur = 0;
    for (int k0 = 0; k0 < K; k0 += 32) {
        bool more = (k0 + 32 < K);
        if (more) stage(cur ^ 1, k0 + 32);
        const u16* base = &lds[cur * 6144];
        bf16x8 af[2], bfm[4];
#pragma unroll
        for (int i = 0; i < 2; ++i)
            af[i] = *(const bf16x8*)&base[(wm + i * 16 + fr) * 32 + kb];
#pragma unroll
        for (int j = 0; j < 4; ++j)
            bfm[j] = *(const bf16x8*)&base[2048 + (wn + j * 16 + fr) * 32 + kb];
#pragma unroll
        for (int i = 0; i < 2; ++i)
#pragma unroll
            for (int j = 0; j < 4; ++j)
                acc[i][j] = __builtin_amdgcn_mfma_f32_16x16x32_bf16(af[i], bfm[j], acc[i][j], 0, 0, 0);
        if (more) { __syncthreads(); cur ^= 1; }
    }

    const int qr = (lane >> 4) * 4;
    if (obf16) {
        __syncthreads();   // all ds_reads/loads done before LDS reuse (repack overlaps buf1)
#pragma unroll
        for (int i = 0; i < 2; ++i)
#pragma unroll
            for (int r = 0; r < 4; ++r)
#pragma unroll
                for (int j = 0; j < 4; ++j) {
                    int lcol = wn + j * 16 + fr;
                    int gcol = col0 + lcol;
                    float v = acc[i][j][r];
                    if (bias) v += bias[gcol];
                    if (act == 2) v = geluf(v);
                    else if (act == 1) v = siluf(v);
                    else if (act == 4 && gcol < 256) v = geluf(v);
                    lds[(wm + i * 16 + qr + r) * 128 + lcol] = f2b(v);
                }
        __syncthreads();
        int row = tid >> 2, cc0 = (tid & 3) * 32;   // 4 thr/row x 32 u16 = 128-wide row
        int grow = row0 + row;
        if (grow < M) {
            uint4* dst = (uint4*)((u16*)Cv + (size_t)grow * ldc + col0 + cc0);
            const uint4* sp = (const uint4*)&lds[row * 128 + cc0];
            dst[0] = sp[0]; dst[1] = sp[1]; dst[2] = sp[2]; dst[3] = sp[3];
        }
    } else {
        float* Cf = (float*)Cv;
#pragma unroll
        for (int i = 0; i < 2; ++i)
#pragma unroll
            for (int r = 0; r < 4; ++r) {
                int grow = row0 + wm + i * 16 + qr + r;
                if (grow >= M) continue;
#pragma unroll
                for (int j = 0; j < 4; ++j) {
                    int gcol = col0 + wn + j * 16 + fr;
                    float v = acc[i][j][r];
                    if (bias) v += bias[gcol];
                    if (act == 2) v = geluf(v);
                    else if (act == 1) v = siluf(v);
                    Cf[(size_t)grow * ldc + gcol] = v;
                }
            }
    }
}

// ---------------- fused FFN12 + swiglu: C[:,j] = silu(A@W12a_j) * (A@W12b_j) ------------
// A: M x 256 bf16. Wt: 2048 x 256 bf16 (rows 0..1023 = a-cols, 1024..2047 = b-cols).
// C: M x 1024 bf16. Tile 64 rows x 64 cols, 2-phase dbuf. grid = (16, ceil(M/64)).
__global__ __launch_bounds__(256) void gemm_ffn12(
    const u16* __restrict__ A, const u16* __restrict__ Wt,
    u16* __restrict__ C, int M)
{
    __shared__ u16 sm[12288];  // 2 x (A[64][32]+B1[64][32]+B2[64][32]); out reuse [64][64]

    const int tid  = threadIdx.x;
    const int lane = tid & 63;
    const int wave = tid >> 6;
    const int row0 = blockIdx.y * 64;
    const int col0 = blockIdx.x * 64;
    const int wm   = (wave >> 1) * 32;
    const int wn   = (wave & 1) * 32;

    f32x4 accA[2][2], accB[2][2];
#pragma unroll
    for (int i = 0; i < 2; ++i)
#pragma unroll
        for (int j = 0; j < 2; ++j) { accA[i][j] = (f32x4)0.0f; accB[i][j] = (f32x4)0.0f; }

    const int kc = (lane & 3) * 8;
    const int rr = wave * 16 + (lane >> 2);
    const u16* pa  = A + (size_t)imin(row0 + rr, M - 1) * 256 + kc;
    const u16* pb1 = Wt + (size_t)(col0 + rr) * 256 + kc;
    const u16* pb2 = Wt + (size_t)(1024 + col0 + rr) * 256 + kc;

    const int kb = (lane >> 4) * 8;
    const int fr = lane & 15;

    auto stage = [&](int buf, int k0) {
        u16* base = &sm[buf * 6144];
        gload16(pa + k0, base + wave * 512);
        gload16(pb1 + k0, base + 2048 + wave * 512);
        gload16(pb2 + k0, base + 4096 + wave * 512);
    };

    stage(0, 0);
    __syncthreads();
    int cur = 0;
#pragma unroll 1
    for (int k0 = 0; k0 < 256; k0 += 32) {
        bool more = (k0 + 32 < 256);
        if (more) stage(cur ^ 1, k0 + 32);
        const u16* base = &sm[cur * 6144];
        bf16x8 af[2], b1f[2], b2f_[2];
#pragma unroll
        for (int i = 0; i < 2; ++i)
            af[i] = *(const bf16x8*)&base[(wm + i * 16 + fr) * 32 + kb];
#pragma unroll
        for (int j = 0; j < 2; ++j) {
            b1f[j] = *(const bf16x8*)&base[2048 + (wn + j * 16 + fr) * 32 + kb];
            b2f_[j] = *(const bf16x8*)&base[4096 + (wn + j * 16 + fr) * 32 + kb];
        }
#pragma unroll
        for (int i = 0; i < 2; ++i)
#pragma unroll
            for (int j = 0; j < 2; ++j) {
                accA[i][j] = __builtin_amdgcn_mfma_f32_16x16x32_bf16(af[i], b1f[j], accA[i][j], 0, 0, 0);
                accB[i][j] = __builtin_amdgcn_mfma_f32_16x16x32_bf16(af[i], b2f_[j], accB[i][j], 0, 0, 0);
            }
        if (more) { __syncthreads(); cur ^= 1; }
    }

    const int qr = (lane >> 4) * 4;
    __syncthreads();
#pragma unroll
    for (int i = 0; i < 2; ++i)
#pragma unroll
        for (int r = 0; r < 4; ++r)
#pragma unroll
            for (int j = 0; j < 2; ++j) {
                float a = accA[i][j][r], b = accB[i][j][r];
                sm[(wm + i * 16 + qr + r) * 64 + wn + j * 16 + fr] = f2b(siluf(a) * b);
            }
    __syncthreads();
    int row = tid >> 2, cc0 = (tid & 3) * 16;   // 4 thr/row x 16 u16 = 64-wide row
    int grow = row0 + row;
    if (grow < M) {
        uint4* dst = (uint4*)(C + (size_t)grow * 1024 + col0 + cc0);
        const uint4* sp = (const uint4*)&sm[row * 64 + cc0];
        dst[0] = sp[0]; dst[1] = sp[1];
    }
}

// ---------------- fused FFN-out + final: out = [eae+] h2 + gate*(A@Wout) ---------------
// A: M x 1024 bf16. Bt: 256 x 1024 bf16. out: M x 256 fp32.
// Tile 64 rows x 128 cols, 2-phase dbuf. grid = (2, ceil(M/64)).
__global__ __launch_bounds__(256) void gemm_out_final(
    const u16* __restrict__ A, const u16* __restrict__ Bt,
    const float* __restrict__ eae, const u16* __restrict__ h2,
    const u16* __restrict__ gate, int ldg, int goff,
    float* __restrict__ out, int M)
{
    __shared__ u16 lds[12288];   // 2 x (A[64][32] + B[128][32])

    const int tid  = threadIdx.x;
    const int lane = tid & 63;
    const int wave = tid >> 6;
    const int row0 = blockIdx.y * 64;
    const int col0 = blockIdx.x * 128;
    const int wm   = (wave >> 1) * 32;
    const int wn   = (wave & 1) * 64;

    f32x4 acc[2][4];
#pragma unroll
    for (int i = 0; i < 2; ++i)
#pragma unroll
        for (int j = 0; j < 4; ++j) acc[i][j] = (f32x4)0.0f;

    const int kc = (lane & 3) * 8;
    const int rr = wave * 16 + (lane >> 2);
    const int rb1 = (wave + 4) * 16 + (lane >> 2);
    const u16* pa  = A + (size_t)imin(row0 + rr, M - 1) * 1024 + kc;
    const u16* pb0 = Bt + (size_t)(col0 + rr) * 1024 + kc;
    const u16* pb1 = Bt + (size_t)(col0 + rb1) * 1024 + kc;

    const int kb = (lane >> 4) * 8;
    const int fr = lane & 15;

    auto stage = [&](int buf, int k0) {
        u16* base = &lds[buf * 6144];
        gload16(pa + k0, base + wave * 512);
        gload16(pb0 + k0, base + 2048 + wave * 512);
        gload16(pb1 + k0, base + 2048 + (wave + 4) * 512);
    };

    stage(0, 0);
    __syncthreads();
    int cur = 0;
#pragma unroll 1
    for (int k0 = 0; k0 < 1024; k0 += 32) {
        bool more = (k0 + 32 < 1024);
        if (more) stage(cur ^ 1, k0 + 32);
        const u16* base = &lds[cur * 6144];
        bf16x8 af[2], bfm[4];
#pragma unroll
        for (int i = 0; i < 2; ++i)
            af[i] = *(const bf16x8*)&base[(wm + i * 16 + fr) * 32 + kb];
#pragma unroll
        for (int j = 0; j < 4; ++j)
            bfm[j] = *(const bf16x8*)&base[2048 + (wn + j * 16 + fr) * 32 + kb];
#pragma unroll
        for (int i = 0; i < 2; ++i)
#pragma unroll
            for (int j = 0; j < 4; ++j)
                acc[i][j] = __builtin_amdgcn_mfma_f32_16x16x32_bf16(af[i], bfm[j], acc[i][j], 0, 0, 0);
        if (more) { __syncthreads(); cur ^= 1; }
    }

    const int qr = (lane >> 4) * 4;
#pragma unroll
    for (int i = 0; i < 2; ++i)
#pragma unroll
        for (int r = 0; r < 4; ++r) {
            int grow = row0 + wm + i * 16 + qr + r;
            if (grow >= M) continue;
#pragma unroll
            for (int j = 0; j < 4; ++j) {
                int gcol = col0 + wn + j * 16 + fr;
                size_t idx = (size_t)grow * 256 + gcol;
                float v = acc[i][j][r] * b2f(gate[(size_t)grow * ldg + goff + gcol]) + b2f(h2[idx]);
                if (eae) v += eae[idx];
                out[idx] = v;
            }
        }
}

// ---------------- weight transpose-convert: Wt[n*K+k] = bf16(W[k*N+n]) ------------------
__global__ __launch_bounds__(256) void k_wconv(
    const float* __restrict__ W, u16* __restrict__ Wt, int K, int N)
{
    int i = blockIdx.x * 256 + threadIdx.x;
    if (i >= K * N) return;
    int n = i / K, k = i - n * K;
    Wt[i] = f2b(W[(size_t)k * N + n]);
}

// ---------------- elementwise converters -----------------------------------------------
__global__ __launch_bounds__(256) void k_silu_b16(
    const float* __restrict__ src, u16* __restrict__ dst, long long n4)
{
    long long i = (long long)blockIdx.x * 256 + threadIdx.x;
    if (i >= n4) return;
    float4 v = ((const float4*)src)[i];
    ushort4 o;
    o.x = f2b(siluf(v.x)); o.y = f2b(siluf(v.y)); o.z = f2b(siluf(v.z)); o.w = f2b(siluf(v.w));
    ((ushort4*)dst)[i] = o;
}

// pack [edge_attr(256) | dist(128)] -> bf16 rows of 384
__global__ __launch_bounds__(256) void k_pack_ed(
    const float* __restrict__ ea_, const float* __restrict__ dist,
    u16* __restrict__ out, long long cnt4)
{
    long long i = (long long)blockIdx.x * 256 + threadIdx.x;
    if (i >= cnt4) return;
    long long r = i / 96;
    int c4 = (int)(i - r * 96) * 4;
    float4 v = (c4 < 256) ? *(const float4*)(ea_ + r * 256 + c4)
                          : *(const float4*)(dist + r * 128 + (c4 - 256));
    ushort4 o;
    o.x = f2b(v.x); o.y = f2b(v.y); o.z = f2b(v.z); o.w = f2b(v.w);
    *(ushort4*)(out + r * 384 + c4) = o;
}

// ---------------- LN + modulate (bf16 shift/scale) -> bf16 ------------------------------
__global__ __launch_bounds__(256) void k_ln_mod_b16(
    const float* __restrict__ X, u16* __restrict__ Y, int M,
    const u16* __restrict__ ssb, int ldss, int shoff, int scoff)
{
    int row = (blockIdx.x << 2) + (threadIdx.x >> 6);
    if (row >= M) return;
    int lane = threadIdx.x & 63;
    const float* xr = X + (size_t)row * HID + lane * 4;
    float x0 = xr[0], x1 = xr[1], x2 = xr[2], x3 = xr[3];
    float s = x0 + x1 + x2 + x3;
    float q = x0 * x0 + x1 * x1 + x2 * x2 + x3 * x3;
#pragma unroll
    for (int o = 32; o; o >>= 1) { s += __shfl_xor(s, o, 64); q += __shfl_xor(q, o, 64); }
    float m = s * (1.f / HID);
    float r = rsqrtf(q * (1.f / HID) - m * m + 1e-6f);
    const u16* sp = ssb + (size_t)row * ldss;
    ushort4 sh = *(const ushort4*)(sp + shoff + lane * 4);
    ushort4 sc = *(const ushort4*)(sp + scoff + lane * 4);
    ushort4 o;
    o.x = f2b((x0 - m) * r * (1.f + b2f(sc.x)) + b2f(sh.x));
    o.y = f2b((x1 - m) * r * (1.f + b2f(sc.y)) + b2f(sh.y));
    o.z = f2b((x2 - m) * r * (1.f + b2f(sc.z)) + b2f(sh.z));
    o.w = f2b((x3 - m) * r * (1.f + b2f(sc.w)) + b2f(sh.w));
    ((ushort4*)(Y + (size_t)row * HID))[lane] = o;
}

// ----- Y(bf16) = modulate( ln(A + gate.*Bv) [*g + b], shift, scale ); gate/ss bf16 ------
__global__ __launch_bounds__(256) void k_ln_mod_resid_b16(
    const float* __restrict__ A, const float* __restrict__ Bv, u16* __restrict__ Y, int M,
    const u16* __restrict__ gb, int ldg, int goff,
    const u16* __restrict__ ssb, int ldss, int shoff, int scoff,
    const float* __restrict__ gw, const float* __restrict__ bw)
{
    int row = (blockIdx.x << 2) + (threadIdx.x >> 6);
    if (row >= M) return;
    int lane = threadIdx.x & 63;
    const float* ar = A + (size_t)row * HID + lane * 4;
    const float* br = Bv + (size_t)row * HID + lane * 4;
    ushort4 gp = *(const ushort4*)(gb + (size_t)row * ldg + goff + lane * 4);
    float t0 = ar[0] + b2f(gp.x) * br[0];
    float t1 = ar[1] + b2f(gp.y) * br[1];
    float t2 = ar[2] + b2f(gp.z) * br[2];
    float t3 = ar[3] + b2f(gp.w) * br[3];
    float s = t0 + t1 + t2 + t3;
    float q = t0 * t0 + t1 * t1 + t2 * t2 + t3 * t3;
#pragma unroll
    for (int o = 32; o; o >>= 1) { s += __shfl_xor(s, o, 64); q += __shfl_xor(q, o, 64); }
    float m = s * (1.f / HID);
    float r = rsqrtf(q * (1.f / HID) - m * m + 1e-6f);
    float n0 = (t0 - m) * r, n1 = (t1 - m) * r, n2 = (t2 - m) * r, n3 = (t3 - m) * r;
    if (gw) {
        const float* g4 = gw + lane * 4;
        const float* b4 = bw + lane * 4;
        n0 = n0 * g4[0] + b4[0]; n1 = n1 * g4[1] + b4[1];
        n2 = n2 * g4[2] + b4[2]; n3 = n3 * g4[3] + b4[3];
    }
    const u16* sp = ssb + (size_t)row * ldss;
    ushort4 sh = *(const ushort4*)(sp + shoff + lane * 4);
    ushort4 sc = *(const ushort4*)(sp + scoff + lane * 4);
    ushort4 o;
    o.x = f2b(n0 * (1.f + b2f(sc.x)) + b2f(sh.x));
    o.y = f2b(n1 * (1.f + b2f(sc.y)) + b2f(sh.y));
    o.z = f2b(n2 * (1.f + b2f(sc.z)) + b2f(sh.z));
    o.w = f2b(n3 * (1.f + b2f(sc.w)) + b2f(sh.w));
    ((ushort4*)(Y + (size_t)row * HID))[lane] = o;
}

// ---------------- attention ------------------------------------------------------------
// alpha only (no atomics): alpha[e,h] = sum_d q*k*ea / sqrt(32)
__global__ __launch_bounds__(256) void attn_alpha_k(
    const u16* __restrict__ qkv, const u16* __restrict__ ea, int lde,
    const int* __restrict__ src, const int* __restrict__ tgt,
    float* __restrict__ alpha)
{
    int e = blockIdx.x;
    int t = threadIdx.x;
    int h = t >> 5, d = t & 31;
    int s = src[e], g = tgt[e];
    float qv = b2f(qkv[(size_t)s * 768 + h * 32 + d]);
    float kv = b2f(qkv[(size_t)g * 768 + 256 + h * 32 + d]);
    float wv = b2f(ea[(size_t)e * lde + t]);
    float v = qv * kv * wv;
#pragma unroll
    for (int o = 16; o; o >>= 1) v += __shfl_xor(v, o, 32);
    if (d == 0) alpha[(size_t)e * 8 + h] = v * 0.17677669529663687f;  // 1/sqrt(32)
}

// ---------------- CSR build ------------------------------------------------------------
__global__ __launch_bounds__(256) void k_hist(
    const int* __restrict__ tgt, int* __restrict__ counts, int E)
{
    int i = blockIdx.x * 256 + threadIdx.x;
    if (i < E) atomicAdd(&counts[tgt[i]], 1);
}

// single block: exclusive scan of counts[0..Nn) -> offsets[0..Nn]
__global__ __launch_bounds__(256) void k_scan(
    const int* __restrict__ counts, int* __restrict__ offsets, int Nn)
{
    __shared__ int part[256];
    __shared__ int pref[257];
    int t = threadIdx.x;
    int chunk = (Nn + 255) / 256;
    int lo = t * chunk, hi = imin(lo + chunk, Nn);
    int s = 0;
    for (int i = lo; i < hi; ++i) s += counts[i];
    part[t] = s;
    __syncthreads();
    if (t == 0) {
        int run = 0;
        for (int i = 0; i < 256; ++i) { pref[i] = run; run += part[i]; }
        pref[256] = run;
        offsets[Nn] = run;
    }
    __syncthreads();
    int run = pref[t];
    for (int i = lo; i < hi; ++i) { offsets[i] = run; run += counts[i]; }
}

__global__ __launch_bounds__(256) void k_scatter(
    const int* __restrict__ tgt, int* __restrict__ cursor,
    int* __restrict__ eidlist, int E)
{
    int i = blockIdx.x * 256 + threadIdx.x;
    if (i < E) {
        int pos = atomicAdd(&cursor[tgt[i]], 1);
        eidlist[pos] = i;
    }
}

// per (node, head): amax and 1/sum(exp) over CSR edge list
__global__ __launch_bounds__(256) void k_amax_den(
    const float* __restrict__ alpha, const int* __restrict__ offsets,
    const int* __restrict__ eidlist, float* __restrict__ amaxF,
    float* __restrict__ invden, int NH8)
{
    int i = blockIdx.x * 256 + threadIdx.x;
    if (i >= NH8) return;
    int n = i >> 3, h = i & 7;
    int b = offsets[n], e = offsets[n + 1];
    float m = -1e30f;
    for (int k = b; k < e; ++k) m = fmaxf(m, alpha[(size_t)eidlist[k] * 8 + h]);
    float s = 0.f;
    for (int k = b; k < e; ++k) s += __expf(alpha[(size_t)eidlist[k] * 8 + h] - m);
    amaxF[i] = m;
    invden[i] = (s > 0.f) ? 1.f / s : 0.f;
}

// alpha[i] <- normalized softmax weight (streaming, no atomics)
__global__ __launch_bounds__(256) void k_norm(
    float* __restrict__ alpha, const float* __restrict__ amaxF,
    const float* __restrict__ invden, const int* __restrict__ tgt, int EH)
{
    int i = blockIdx.x * 256 + threadIdx.x;
    if (i >= EH) return;
    int e = i >> 3, h = i & 7;
    int g = tgt[e];
    alpha[i] = __expf(alpha[i] - amaxF[(size_t)g * 8 + h]) * invden[(size_t)g * 8 + h];
}

// message pass via CSR: hat[n,c] = V[n,c] * sum_{e in CSR[n]} e1[e,c]*w[e,h]
__global__ __launch_bounds__(256) void attn_msg_csr(
    const u16* __restrict__ qkv, const u16* __restrict__ ea1,
    const float* __restrict__ alpha, const int* __restrict__ offsets,
    const int* __restrict__ eidlist, float* __restrict__ hattn)
{
    int n = blockIdx.x;
    int c = threadIdx.x;
    int h = c >> 5;
    int b = offsets[n], e = offsets[n + 1];
    float acc = 0.f;
    for (int k = b; k < e; ++k) {
        int eid = eidlist[k];
        float w = alpha[(size_t)eid * 8 + h];
        acc += b2f(ea1[(size_t)eid * 512 + 256 + c]) * w;
    }
    hattn[(size_t)n * 256 + c] = b2f(qkv[(size_t)n * 768 + 512 + c]) * acc;
}

// ---------------- gsum -----------------------------------------------------------------
__global__ __launch_bounds__(256) void k_gsum_b16(
    const float* __restrict__ hattn, const int* __restrict__ src, const int* __restrict__ tgt,
    u16* __restrict__ g, long long cnt4)
{
    long long i = (long long)blockIdx.x * 256 + threadIdx.x;
    if (i >= cnt4) return;
    long long e = i >> 6;
    int c4 = (int)(i & 63) * 4;
    float4 a = *(const float4*)(hattn + (size_t)src[e] * 256 + c4);
    float4 b = *(const float4*)(hattn + (size_t)tgt[e] * 256 + c4);
    ushort4 o;
    o.x = f2b(a.x + b.x); o.y = f2b(a.y + b.y); o.z = f2b(a.z + b.z); o.w = f2b(a.w + b.w);
    ((ushort4*)g)[i] = o;
}

// ---------------------------------------------------------------------------------------
static inline void gemm(hipStream_t st, const u16* A, int lda, const u16* Bt, int ldb,
                        void* C, int ldc, int M, int N, int K,
                        const float* bias, int act, int obf16)
{
    dim3 g(N / 128, (M + 63) / 64);
    hipLaunchKernelGGL(gemm_mfma, g, dim3(256), 0, st, A, lda, Bt, ldb, C, ldc, M, N, K,
                       bias, act, obf16);
}

extern "C" void kernel_launch(void* const* d_in, const int* in_sizes, int n_in,
                              void* d_out, int out_size, void* d_ws, size_t ws_size,
                              hipStream_t stream)
{
    const int Nn = in_sizes[0];
    const int E = in_sizes[3] / HID;

    const float* x        = (const float*)d_in[1];
    const float* t_emb_h  = (const float*)d_in[2];
    const float* edge_attr= (const float*)d_in[3];
    const int*   eidx     = (const int*)d_in[4];
    const float* t_emb_e  = (const float*)d_in[5];
    const float* dist     = (const float*)d_in[6];
    const float* W_ee     = (const float*)d_in[7];
    const float* b_ee     = (const float*)d_in[8];
    const float* W_ad     = (const float*)d_in[9];
    const float* b_ad     = (const float*)d_in[10];
    const float* W_ade    = (const float*)d_in[11];
    const float* b_ade    = (const float*)d_in[12];
    const float* W_qkv    = (const float*)d_in[13];
    const float* W_e0     = (const float*)d_in[14];
    const float* W_e1     = (const float*)d_in[15];
    const float* W_n2e    = (const float*)d_in[16];
    const float* b_n2e    = (const float*)d_in[17];
    const float* g_ln     = (const float*)d_in[18];
    const float* b_ln     = (const float*)d_in[19];
    const float* W_f12    = (const float*)d_in[20];
    const float* W_fout   = (const float*)d_in[21];
    const float* W_fe12   = (const float*)d_in[22];
    const float* W_feout  = (const float*)d_in[23];

    const int* src = eidx;
    const int* tgt = eidx + E;

    float* outN = (float*)d_out;
    float* outE = (float*)d_out + (size_t)Nn * 256;   // also holds edge_attr_e (prev_edge_attr)

    // ---- persistent workspace ----
    char* W = (char*)d_ws;
    size_t off = 0;
    auto alloc = [&](size_t bytes) -> size_t {
        size_t o = off; off += (bytes + 255) & ~(size_t)255; return o;
    };
    float*    alpha = (float*)(W + alloc((size_t)E * 8 * 4));
    float*    amaxF = (float*)(W + alloc((size_t)Nn * 8 * 4));
    float*    invden= (float*)(W + alloc((size_t)Nn * 8 * 4));
    float*    hat   = (float*)(W + alloc((size_t)Nn * 256 * 4));
    int*      offs  = (int*)(W + alloc((size_t)(Nn + 1) * 4));
    int*      cursor= (int*)(W + alloc((size_t)Nn * 4));
    int*      eidl  = (int*)(W + alloc((size_t)E * 4));
    u16*      qkvb  = (u16*)(W + alloc((size_t)Nn * 768 * 2));
    u16*      sth   = (u16*)(W + alloc((size_t)Nn * 256 * 2));
    u16*      steb  = (u16*)(W + alloc((size_t)E * 256 * 2));    // silu(t_emb_e)
    u16*      ea1b  = (u16*)(W + alloc((size_t)E * 512 * 2));    // [gelu(e_mod@W_e0) | e_mod@W_e1]
    u16*      adnb  = (u16*)(W + alloc((size_t)Nn * 1536 * 2));  // full node adaln
    u16*      xmb   = (u16*)(W + alloc((size_t)Nn * 256 * 2));
    u16*      h2nb  = (u16*)(W + alloc((size_t)Nn * 256 * 2));
    u16*      cnb   = (u16*)(W + alloc((size_t)Nn * 1024 * 2));
    // bf16 transposed weights (N x K)
    u16* weet   = (u16*)(W + alloc((size_t)256 * 384 * 2));
    u16* wadt   = (u16*)(W + alloc((size_t)1536 * 256 * 2));
    u16* wadet  = (u16*)(W + alloc((size_t)1536 * 256 * 2));
    u16* wqkvt  = (u16*)(W + alloc((size_t)768 * 256 * 2));
    u16* we01t  = (u16*)(W + alloc((size_t)512 * 256 * 2));      // [W_e0^T ; W_e1^T]
    u16* wn2et  = (u16*)(W + alloc((size_t)256 * 256 * 2));
    u16* wf12t  = (u16*)(W + alloc((size_t)2048 * 256 * 2));
    u16* wfoutt = (u16*)(W + alloc((size_t)256 * 1024 * 2));
    u16* wfe12t = (u16*)(W + alloc((size_t)2048 * 256 * 2));
    u16* wfeoutt= (u16*)(W + alloc((size_t)256 * 1024 * 2));

    char* pool = W + off;
    size_t poolB = (ws_size > off) ? (ws_size - off) : 0;
    auto chunkRowsB = [&](size_t bytesPerRow, int total) -> int {
        long c = (long)(poolB / bytesPerRow);
        c = (c / 256) * 256;
        if (c < 256) c = 256;
        if (c > total) c = (long)total;
        return (int)c;
    };

    // ---- CSR build by tgt (counts -> offsets -> eidlist) ----
    hipMemsetAsync(cursor, 0, (size_t)Nn * 4, stream);
    hipLaunchKernelGGL(k_hist, dim3((E + 255) / 256), dim3(256), 0, stream, tgt, cursor, E);
    hipLaunchKernelGGL(k_scan, dim3(1), dim3(256), 0, stream, cursor, offs, Nn);
    hipMemcpyAsync(cursor, offs, (size_t)Nn * 4, hipMemcpyDeviceToDevice, stream);
    hipLaunchKernelGGL(k_scatter, dim3((E + 255) / 256), dim3(256), 0, stream,
                       tgt, cursor, eidl, E);

    // ---- weight conversion ----
    {
        struct WC { const float* w; u16* wt; int K, N; } wl[] = {
            { W_ee,    weet,   384, 256 },
            { W_ad,    wadt,   256, 1536 },
            { W_ade,   wadet,  256, 1536 },
            { W_qkv,   wqkvt,  256, 768 },
            { W_e0,    we01t,  256, 256 },
            { W_e1,    we01t + 256 * 256, 256, 256 },
            { W_n2e,   wn2et,  256, 256 },
            { W_f12,   wf12t,  256, 2048 },
            { W_fout,  wfoutt, 1024, 256 },
            { W_fe12,  wfe12t, 256, 2048 },
            { W_feout, wfeoutt,1024, 256 },
        };
        for (auto& e : wl) {
            int cnt = e.K * e.N;
            hipLaunchKernelGGL(k_wconv, dim3((cnt + 255) / 256), dim3(256), 0, stream,
                               e.w, e.wt, e.K, e.N);
        }
    }

    // silu conversions (persistent)
    hipLaunchKernelGGL(k_silu_b16, dim3((unsigned)(((long long)Nn * 64 + 255) / 256)), dim3(256),
                       0, stream, t_emb_h, sth, (long long)Nn * 64);
    hipLaunchKernelGGL(k_silu_b16, dim3((unsigned)(((long long)E * 64 + 255) / 256)), dim3(256),
                       0, stream, t_emb_e, steb, (long long)E * 64);

    // ---- phase 1: node pre ----
    gemm(stream, sth, 256, wadt, 256, adnb, 1536, Nn, 1536, 256, b_ad, 0, 1);
    hipLaunchKernelGGL(k_ln_mod_b16, dim3((Nn + 3) / 4), dim3(256), 0, stream,
                       x, xmb, Nn, adnb, 1536, 0, 256);
    gemm(stream, xmb, 256, wqkvt, 256, qkvb, 768, Nn, 768, 256, nullptr, 0, 1);

    // ---- phase 2: edge pre ----
    {
        int C = chunkRowsB(1536 + 1024 + 512, E);
        char* p = pool;
        u16* eab2 = (u16*)p; p += (size_t)C * 1536;   // packed [edge_attr|dist] K=384 (bf16)
        u16* emsb = (u16*)p; p += (size_t)C * 1024;   // adaln_e[:,0:512) (bf16)
        u16* emod = (u16*)p;                          // C x 256 bf16
        for (int s = 0; s < E; s += C) {
            int cc = (E - s < C) ? (E - s) : C;
            float* eaeC = outE + (size_t)s * 256;
            hipLaunchKernelGGL(k_pack_ed, dim3((unsigned)(((long long)cc * 96 + 255) / 256)),
                               dim3(256), 0, stream, edge_attr + (size_t)s * 256,
                               dist + (size_t)s * 128, eab2, (long long)cc * 96);
            gemm(stream, eab2, 384, weet, 384, eaeC, 256, cc, 256, 384, b_ee, 0, 0);
            gemm(stream, steb + (size_t)s * 256, 256, wadet, 256, emsb, 512, cc, 512, 256,
                 b_ade, 0, 1);
            hipLaunchKernelGGL(k_ln_mod_b16, dim3((cc + 3) / 4), dim3(256), 0, stream,
                               eaeC, emod, cc, emsb, 512, 0, 256);
            gemm(stream, emod, 256, we01t, 256, ea1b + (size_t)s * 512, 512, cc, 512, 256,
                 nullptr, 4, 1);
            hipLaunchKernelGGL(attn_alpha_k, dim3(cc), dim3(256), 0, stream,
                               qkvb, ea1b + (size_t)s * 512, 512, src + s, tgt + s,
                               alpha + (size_t)s * 8);
        }
    }

    // ---- phase 3: softmax stats + normalize (no atomics) ----
    hipLaunchKernelGGL(k_amax_den, dim3((Nn * 8 + 255) / 256), dim3(256), 0, stream,
                       alpha, offs, eidl, amaxF, invden, Nn * 8);
    hipLaunchKernelGGL(k_norm, dim3((E * 8 + 255) / 256), dim3(256), 0, stream,
                       alpha, amaxF, invden, tgt, E * 8);

    // ---- phase 4: message pass via CSR (no atomics) ----
    hipLaunchKernelGGL(attn_msg_csr, dim3(Nn), dim3(256), 0, stream,
                       qkvb, ea1b, alpha, offs, eidl, hat);

    // ---- phase 5: node finish ----
    hipLaunchKernelGGL(k_ln_mod_resid_b16, dim3((Nn + 3) / 4), dim3(256), 0, stream,
                       x, hat, h2nb, Nn, adnb, 1536, 512, adnb, 1536, 768, 1024, g_ln, b_ln);
    hipLaunchKernelGGL(gemm_ffn12, dim3(16, (Nn + 63) / 64), dim3(256), 0, stream,
                       h2nb, wf12t, cnb, Nn);
    hipLaunchKernelGGL(gemm_out_final, dim3(2, (Nn + 63) / 64), dim3(256), 0, stream,
                       cnb, wfoutt, (const float*)nullptr, h2nb, adnb, 1536, 1280, outN, Nn);

    // ---- phase 6: edge finish ----
    {
        int C = chunkRowsB(512 + 2048 + 1024 + 512 + 2048, E);
        char* p = pool;
        u16*   gsum = (u16*)p;  p += (size_t)C * 512;
        u16*   em2b = (u16*)p;  p += (size_t)C * 2048;   // adaln_e[:,512:1536)
        float* hep  = (float*)p; p += (size_t)C * 1024;
        u16*   h2e  = (u16*)p;  p += (size_t)C * 512;
        u16*   cne  = (u16*)p;                            // swiglu out C x 1024
        for (int s = 0; s < E; s += C) {
            int cc = (E - s < C) ? (E - s) : C;
            hipLaunchKernelGGL(k_gsum_b16, dim3((unsigned)(((long long)cc * 64 + 255) / 256)),
                               dim3(256), 0, stream, hat, src + s, tgt + s, gsum, (long long)cc * 64);
            gemm(stream, gsum, 256, wn2et, 256, hep, 256, cc, 256, 256, b_n2e, 0, 0);
            gemm(stream, steb + (size_t)s * 256, 256, wadet + 512 * 256, 256, em2b, 1024,
                 cc, 1024, 256, b_ade + 512, 0, 1);
            hipLaunchKernelGGL(k_ln_mod_resid_b16, dim3((cc + 3) / 4), dim3(256), 0, stream,
                               edge_attr + (size_t)s * 256, hep, h2e, cc,
                               em2b, 1024, 0, em2b, 1024, 256, 512, nullptr, nullptr);
            hipLaunchKernelGGL(gemm_ffn12, dim3(16, (cc + 63) / 64), dim3(256), 0, stream,
                               h2e, wfe12t, cne, cc);
            hipLaunchKernelGGL(gemm_out_final, dim3(2, (cc + 63) / 64), dim3(256), 0, stream,
                               cne, wfeoutt, outE + (size_t)s * 256, h2e,
                               em2b, 1024, 768, outE + (size_t)s * 256, cc);
        }
    }
    (void)n_in; (void)out_size;
}

// Round 14
// 2240.095 us; speedup vs baseline: 1.0464x; 1.0464x over previous
//
#include <hip/hip_runtime.h>

#define HID 256

typedef unsigned short u16;
typedef __attribute__((ext_vector_type(8))) short bf16x8;
typedef __attribute__((ext_vector_type(4))) float f32x4;

__device__ __forceinline__ float siluf(float x) { return x / (1.f + __expf(-x)); }
// tanh-approx gelu via sigmoid identity: 0.5x(1+tanh(z)) == x*sigmoid(2z)
__device__ __forceinline__ float geluf(float x) {
    return x / (1.f + __expf(-(1.59576912f * x + 0.07135481f * x * x * x)));
}
__device__ __forceinline__ u16 f2b(float x) {
    unsigned u = __float_as_uint(x);
    unsigned r = u + 0x7FFFu + ((u >> 16) & 1u);
    return (u16)(r >> 16);
}
__device__ __forceinline__ float b2f(u16 h) {
    return __uint_as_float(((unsigned)h) << 16);
}
__device__ __forceinline__ void gload16(const u16* g, u16* l) {
    __builtin_amdgcn_global_load_lds(
        (const __attribute__((address_space(1))) unsigned int*)g,
        (__attribute__((address_space(3))) unsigned int*)l, 16, 0, 0);
}
__device__ __forceinline__ int imin(int a, int b) { return a < b ? a : b; }

// ---------------- bf16 MFMA GEMM: C = act(A @ Bt^T + bias) ------------------------------
// A: M x K bf16 (lda). Bt: N x K bf16 (ldb). 64x128 tile, BK=32, 4 waves 2x2 of 32x64.
// Single-buffered (r12-measured-fast). LDS 16KB: staging 12KB, repack reuse 16KB.
// act: 1=silu, 2=gelu, 4=gelu on global cols [0,256) only. N%128==0, K%32==0.
__global__ __launch_bounds__(256) void gemm_mfma(
    const u16* __restrict__ A, int lda,
    const u16* __restrict__ Bt, int ldb,
    void* __restrict__ Cv, int ldc,
    int M, int N, int K,
    const float* __restrict__ bias, int act, int obf16)
{
    __shared__ u16 lds[8192];   // staging A(2048)+B(4096) u16; repack uses all 8192 u16

    const int tid  = threadIdx.x;
    const int lane = tid & 63;
    const int wave = tid >> 6;
    const int row0 = blockIdx.y * 64;
    const int col0 = blockIdx.x * 128;
    const int wm   = (wave >> 1) * 32;
    const int wn   = (wave & 1) * 64;

    f32x4 acc[2][4];
#pragma unroll
    for (int i = 0; i < 2; ++i)
#pragma unroll
        for (int j = 0; j < 4; ++j) acc[i][j] = (f32x4)0.0f;

    const int kc = (lane & 3) * 8;
    const int rr  = wave * 16 + (lane >> 2);
    const int rb1 = (wave + 4) * 16 + (lane >> 2);
    const u16* pa  = A + (size_t)imin(row0 + rr, M - 1) * lda + kc;
    const u16* pb0 = Bt + (size_t)(col0 + rr) * ldb + kc;
    const u16* pb1 = Bt + (size_t)(col0 + rb1) * ldb + kc;
    u16* la  = &lds[wave * 512];
    u16* lb0 = &lds[2048 + wave * 512];
    u16* lb1 = &lds[2048 + (wave + 4) * 512];

    const int kb = (lane >> 4) * 8;
    const int fr = lane & 15;

    for (int k0 = 0; k0 < K; k0 += 32) {
        gload16(pa + k0, la);
        gload16(pb0 + k0, lb0);
        gload16(pb1 + k0, lb1);
        __syncthreads();

        bf16x8 af[2], bfm[4];
#pragma unroll
        for (int i = 0; i < 2; ++i)
            af[i] = *(const bf16x8*)&lds[(wm + i * 16 + fr) * 32 + kb];
#pragma unroll
        for (int j = 0; j < 4; ++j)
            bfm[j] = *(const bf16x8*)&lds[2048 + (wn + j * 16 + fr) * 32 + kb];
#pragma unroll
        for (int i = 0; i < 2; ++i)
#pragma unroll
            for (int j = 0; j < 4; ++j)
                acc[i][j] = __builtin_amdgcn_mfma_f32_16x16x32_bf16(af[i], bfm[j], acc[i][j], 0, 0, 0);
        __syncthreads();
    }

    const int qr = (lane >> 4) * 4;
    if (obf16) {
#pragma unroll
        for (int i = 0; i < 2; ++i)
#pragma unroll
            for (int r = 0; r < 4; ++r)
#pragma unroll
                for (int j = 0; j < 4; ++j) {
                    int lcol = wn + j * 16 + fr;
                    int gcol = col0 + lcol;
                    float v = acc[i][j][r];
                    if (bias) v += bias[gcol];
                    if (act == 2) v = geluf(v);
                    else if (act == 1) v = siluf(v);
                    else if (act == 4 && gcol < 256) v = geluf(v);
                    lds[(wm + i * 16 + qr + r) * 128 + lcol] = f2b(v);
                }
        __syncthreads();
        int row = tid >> 2, cc0 = (tid & 3) * 32;   // 4 thr/row x 32 u16 = 128-wide row
        int grow = row0 + row;
        if (grow < M) {
            uint4* dst = (uint4*)((u16*)Cv + (size_t)grow * ldc + col0 + cc0);
            const uint4* sp = (const uint4*)&lds[row * 128 + cc0];
            dst[0] = sp[0]; dst[1] = sp[1]; dst[2] = sp[2]; dst[3] = sp[3];
        }
    } else {
        float* Cf = (float*)Cv;
#pragma unroll
        for (int i = 0; i < 2; ++i)
#pragma unroll
            for (int r = 0; r < 4; ++r) {
                int grow = row0 + wm + i * 16 + qr + r;
                if (grow >= M) continue;
#pragma unroll
                for (int j = 0; j < 4; ++j) {
                    int gcol = col0 + wn + j * 16 + fr;
                    float v = acc[i][j][r];
                    if (bias) v += bias[gcol];
                    if (act == 2) v = geluf(v);
                    else if (act == 1) v = siluf(v);
                    Cf[(size_t)grow * ldc + gcol] = v;
                }
            }
    }
}

// ---------------- fused FFN12 + swiglu: C[:,j] = silu(A@W12a_j) * (A@W12b_j) ------------
// A: M x 256 bf16. Wt: 2048 x 256 bf16 (rows 0..1023 = a-cols, 1024..2047 = b-cols).
// C: M x 1024 bf16. Tile 64 rows x 64 cols. grid = (16, ceil(M/64)).
__global__ __launch_bounds__(256) void gemm_ffn12(
    const u16* __restrict__ A, const u16* __restrict__ Wt,
    u16* __restrict__ C, int M)
{
    __shared__ u16 sm[6144];  // A[64][32] + B1[64][32] + B2[64][32]; reuse: out [64][64]
    u16* lsA = sm;            // [64][32]
    u16* lsB1 = sm + 2048;    // [64][32]
    u16* lsB2 = sm + 4096;    // [64][32]

    const int tid  = threadIdx.x;
    const int lane = tid & 63;
    const int wave = tid >> 6;
    const int row0 = blockIdx.y * 64;
    const int col0 = blockIdx.x * 64;
    const int wm   = (wave >> 1) * 32;
    const int wn   = (wave & 1) * 32;

    f32x4 accA[2][2], accB[2][2];
#pragma unroll
    for (int i = 0; i < 2; ++i)
#pragma unroll
        for (int j = 0; j < 2; ++j) { accA[i][j] = (f32x4)0.0f; accB[i][j] = (f32x4)0.0f; }

    const int kc = (lane & 3) * 8;
    const int rr = wave * 16 + (lane >> 2);
    const u16* pa  = A + (size_t)imin(row0 + rr, M - 1) * 256 + kc;
    const u16* pb1 = Wt + (size_t)(col0 + rr) * 256 + kc;
    const u16* pb2 = Wt + (size_t)(1024 + col0 + rr) * 256 + kc;
    u16* la  = &lsA[wave * 512];
    u16* lb1 = &lsB1[wave * 512];
    u16* lb2 = &lsB2[wave * 512];

    const int kb = (lane >> 4) * 8;
    const int fr = lane & 15;

#pragma unroll 1
    for (int k0 = 0; k0 < 256; k0 += 32) {
        gload16(pa + k0, la);
        gload16(pb1 + k0, lb1);
        gload16(pb2 + k0, lb2);
        __syncthreads();

        bf16x8 af[2], b1f[2], b2f_[2];
#pragma unroll
        for (int i = 0; i < 2; ++i)
            af[i] = *(const bf16x8*)&lsA[(wm + i * 16 + fr) * 32 + kb];
#pragma unroll
        for (int j = 0; j < 2; ++j) {
            b1f[j] = *(const bf16x8*)&lsB1[(wn + j * 16 + fr) * 32 + kb];
            b2f_[j] = *(const bf16x8*)&lsB2[(wn + j * 16 + fr) * 32 + kb];
        }
#pragma unroll
        for (int i = 0; i < 2; ++i)
#pragma unroll
            for (int j = 0; j < 2; ++j) {
                accA[i][j] = __builtin_amdgcn_mfma_f32_16x16x32_bf16(af[i], b1f[j], accA[i][j], 0, 0, 0);
                accB[i][j] = __builtin_amdgcn_mfma_f32_16x16x32_bf16(af[i], b2f_[j], accB[i][j], 0, 0, 0);
            }
        __syncthreads();
    }

    const int qr = (lane >> 4) * 4;
#pragma unroll
    for (int i = 0; i < 2; ++i)
#pragma unroll
        for (int r = 0; r < 4; ++r)
#pragma unroll
            for (int j = 0; j < 2; ++j) {
                float a = accA[i][j][r], b = accB[i][j][r];
                sm[(wm + i * 16 + qr + r) * 64 + wn + j * 16 + fr] = f2b(siluf(a) * b);
            }
    __syncthreads();
    int row = tid >> 2, cc0 = (tid & 3) * 16;   // 4 thr/row x 16 u16 = 64-wide row
    int grow = row0 + row;
    if (grow < M) {
        uint4* dst = (uint4*)(C + (size_t)grow * 1024 + col0 + cc0);
        const uint4* sp = (const uint4*)&sm[row * 64 + cc0];
        dst[0] = sp[0]; dst[1] = sp[1];
    }
}

// ---------------- fused FFN-out + final: out = [eae(bf16) +] h2 + gate*(A@Wout) --------
// A: M x 1024 bf16. Bt: 256 x 1024 bf16. out: M x 256 fp32.
// Tile 64 rows x 128 cols, waves 2x2 of 32x64. grid = (2, ceil(M/64)).
__global__ __launch_bounds__(256) void gemm_out_final(
    const u16* __restrict__ A, const u16* __restrict__ Bt,
    const u16* __restrict__ eae, const u16* __restrict__ h2,
    const u16* __restrict__ gate, int ldg, int goff,
    float* __restrict__ out, int M)
{
    __shared__ u16 lds[6144];   // A[64][32] + B[128][32]

    const int tid  = threadIdx.x;
    const int lane = tid & 63;
    const int wave = tid >> 6;
    const int row0 = blockIdx.y * 64;
    const int col0 = blockIdx.x * 128;
    const int wm   = (wave >> 1) * 32;
    const int wn   = (wave & 1) * 64;

    f32x4 acc[2][4];
#pragma unroll
    for (int i = 0; i < 2; ++i)
#pragma unroll
        for (int j = 0; j < 4; ++j) acc[i][j] = (f32x4)0.0f;

    const int kc = (lane & 3) * 8;
    const int rr = wave * 16 + (lane >> 2);
    const int rb1 = (wave + 4) * 16 + (lane >> 2);
    const u16* pa  = A + (size_t)imin(row0 + rr, M - 1) * 1024 + kc;
    const u16* pb0 = Bt + (size_t)(col0 + rr) * 1024 + kc;
    const u16* pb1 = Bt + (size_t)(col0 + rb1) * 1024 + kc;
    u16* la  = &lds[wave * 512];
    u16* lb0 = &lds[2048 + wave * 512];
    u16* lb1 = &lds[2048 + (wave + 4) * 512];

    const int kb = (lane >> 4) * 8;
    const int fr = lane & 15;

#pragma unroll 1
    for (int k0 = 0; k0 < 1024; k0 += 32) {
        gload16(pa + k0, la);
        gload16(pb0 + k0, lb0);
        gload16(pb1 + k0, lb1);
        __syncthreads();

        bf16x8 af[2], bfm[4];
#pragma unroll
        for (int i = 0; i < 2; ++i)
            af[i] = *(const bf16x8*)&lds[(wm + i * 16 + fr) * 32 + kb];
#pragma unroll
        for (int j = 0; j < 4; ++j)
            bfm[j] = *(const bf16x8*)&lds[2048 + (wn + j * 16 + fr) * 32 + kb];
#pragma unroll
        for (int i = 0; i < 2; ++i)
#pragma unroll
            for (int j = 0; j < 4; ++j)
                acc[i][j] = __builtin_amdgcn_mfma_f32_16x16x32_bf16(af[i], bfm[j], acc[i][j], 0, 0, 0);
        __syncthreads();
    }

    const int qr = (lane >> 4) * 4;
#pragma unroll
    for (int i = 0; i < 2; ++i)
#pragma unroll
        for (int r = 0; r < 4; ++r) {
            int grow = row0 + wm + i * 16 + qr + r;
            if (grow >= M) continue;
#pragma unroll
            for (int j = 0; j < 4; ++j) {
                int gcol = col0 + wn + j * 16 + fr;
                size_t idx = (size_t)grow * 256 + gcol;
                float v = acc[i][j][r] * b2f(gate[(size_t)grow * ldg + goff + gcol]) + b2f(h2[idx]);
                if (eae) v += b2f(eae[idx]);
                out[idx] = v;
            }
        }
}

// ---------------- weight transpose-convert: Wt[n*K+k] = bf16(W[k*N+n]) ------------------
__global__ __launch_bounds__(256) void k_wconv(
    const float* __restrict__ W, u16* __restrict__ Wt, int K, int N)
{
    int i = blockIdx.x * 256 + threadIdx.x;
    if (i >= K * N) return;
    int n = i / K, k = i - n * K;
    Wt[i] = f2b(W[(size_t)k * N + n]);
}

// ---------------- elementwise converters -----------------------------------------------
__global__ __launch_bounds__(256) void k_silu_b16(
    const float* __restrict__ src, u16* __restrict__ dst, long long n4)
{
    long long i = (long long)blockIdx.x * 256 + threadIdx.x;
    if (i >= n4) return;
    float4 v = ((const float4*)src)[i];
    ushort4 o;
    o.x = f2b(siluf(v.x)); o.y = f2b(siluf(v.y)); o.z = f2b(siluf(v.z)); o.w = f2b(siluf(v.w));
    ((ushort4*)dst)[i] = o;
}

// pack [edge_attr(256) | dist(128)] -> bf16 rows of 384
__global__ __launch_bounds__(256) void k_pack_ed(
    const float* __restrict__ ea_, const float* __restrict__ dist,
    u16* __restrict__ out, long long cnt4)
{
    long long i = (long long)blockIdx.x * 256 + threadIdx.x;
    if (i >= cnt4) return;
    long long r = i / 96;
    int c4 = (int)(i - r * 96) * 4;
    float4 v = (c4 < 256) ? *(const float4*)(ea_ + r * 256 + c4)
                          : *(const float4*)(dist + r * 128 + (c4 - 256));
    ushort4 o;
    o.x = f2b(v.x); o.y = f2b(v.y); o.z = f2b(v.z); o.w = f2b(v.w);
    *(ushort4*)(out + r * 384 + c4) = o;
}

// ---------------- LN + modulate (bf16 shift/scale) -> bf16, fp32 input ------------------
__global__ __launch_bounds__(256) void k_ln_mod_b16(
    const float* __restrict__ X, u16* __restrict__ Y, int M,
    const u16* __restrict__ ssb, int ldss, int shoff, int scoff)
{
    int row = (blockIdx.x << 2) + (threadIdx.x >> 6);
    if (row >= M) return;
    int lane = threadIdx.x & 63;
    const float* xr = X + (size_t)row * HID + lane * 4;
    float x0 = xr[0], x1 = xr[1], x2 = xr[2], x3 = xr[3];
    float s = x0 + x1 + x2 + x3;
    float q = x0 * x0 + x1 * x1 + x2 * x2 + x3 * x3;
#pragma unroll
    for (int o = 32; o; o >>= 1) { s += __shfl_xor(s, o, 64); q += __shfl_xor(q, o, 64); }
    float m = s * (1.f / HID);
    float r = rsqrtf(q * (1.f / HID) - m * m + 1e-6f);
    const u16* sp = ssb + (size_t)row * ldss;
    ushort4 sh = *(const ushort4*)(sp + shoff + lane * 4);
    ushort4 sc = *(const ushort4*)(sp + scoff + lane * 4);
    ushort4 o;
    o.x = f2b((x0 - m) * r * (1.f + b2f(sc.x)) + b2f(sh.x));
    o.y = f2b((x1 - m) * r * (1.f + b2f(sc.y)) + b2f(sh.y));
    o.z = f2b((x2 - m) * r * (1.f + b2f(sc.z)) + b2f(sh.z));
    o.w = f2b((x3 - m) * r * (1.f + b2f(sc.w)) + b2f(sh.w));
    ((ushort4*)(Y + (size_t)row * HID))[lane] = o;
}

// ---------------- LN + modulate, bf16 input variant -------------------------------------
__global__ __launch_bounds__(256) void k_ln_mod_b16src(
    const u16* __restrict__ X, u16* __restrict__ Y, int M,
    const u16* __restrict__ ssb, int ldss, int shoff, int scoff)
{
    int row = (blockIdx.x << 2) + (threadIdx.x >> 6);
    if (row >= M) return;
    int lane = threadIdx.x & 63;
    ushort4 xv = ((const ushort4*)(X + (size_t)row * HID))[lane];
    float x0 = b2f(xv.x), x1 = b2f(xv.y), x2 = b2f(xv.z), x3 = b2f(xv.w);
    float s = x0 + x1 + x2 + x3;
    float q = x0 * x0 + x1 * x1 + x2 * x2 + x3 * x3;
#pragma unroll
    for (int o = 32; o; o >>= 1) { s += __shfl_xor(s, o, 64); q += __shfl_xor(q, o, 64); }
    float m = s * (1.f / HID);
    float r = rsqrtf(q * (1.f / HID) - m * m + 1e-6f);
    const u16* sp = ssb + (size_t)row * ldss;
    ushort4 sh = *(const ushort4*)(sp + shoff + lane * 4);
    ushort4 sc = *(const ushort4*)(sp + scoff + lane * 4);
    ushort4 o;
    o.x = f2b((x0 - m) * r * (1.f + b2f(sc.x)) + b2f(sh.x));
    o.y = f2b((x1 - m) * r * (1.f + b2f(sc.y)) + b2f(sh.y));
    o.z = f2b((x2 - m) * r * (1.f + b2f(sc.z)) + b2f(sh.z));
    o.w = f2b((x3 - m) * r * (1.f + b2f(sc.w)) + b2f(sh.w));
    ((ushort4*)(Y + (size_t)row * HID))[lane] = o;
}

// ----- Y(bf16) = modulate( ln(A + gate.*Bv) [*g + b], shift, scale ); gate/ss bf16 ------
__global__ __launch_bounds__(256) void k_ln_mod_resid_b16(
    const float* __restrict__ A, const float* __restrict__ Bv, u16* __restrict__ Y, int M,
    const u16* __restrict__ gb, int ldg, int goff,
    const u16* __restrict__ ssb, int ldss, int shoff, int scoff,
    const float* __restrict__ gw, const float* __restrict__ bw)
{
    int row = (blockIdx.x << 2) + (threadIdx.x >> 6);
    if (row >= M) return;
    int lane = threadIdx.x & 63;
    const float* ar = A + (size_t)row * HID + lane * 4;
    const float* br = Bv + (size_t)row * HID + lane * 4;
    ushort4 gp = *(const ushort4*)(gb + (size_t)row * ldg + goff + lane * 4);
    float t0 = ar[0] + b2f(gp.x) * br[0];
    float t1 = ar[1] + b2f(gp.y) * br[1];
    float t2 = ar[2] + b2f(gp.z) * br[2];
    float t3 = ar[3] + b2f(gp.w) * br[3];
    float s = t0 + t1 + t2 + t3;
    float q = t0 * t0 + t1 * t1 + t2 * t2 + t3 * t3;
#pragma unroll
    for (int o = 32; o; o >>= 1) { s += __shfl_xor(s, o, 64); q += __shfl_xor(q, o, 64); }
    float m = s * (1.f / HID);
    float r = rsqrtf(q * (1.f / HID) - m * m + 1e-6f);
    float n0 = (t0 - m) * r, n1 = (t1 - m) * r, n2 = (t2 - m) * r, n3 = (t3 - m) * r;
    if (gw) {
        const float* g4 = gw + lane * 4;
        const float* b4 = bw + lane * 4;
        n0 = n0 * g4[0] + b4[0]; n1 = n1 * g4[1] + b4[1];
        n2 = n2 * g4[2] + b4[2]; n3 = n3 * g4[3] + b4[3];
    }
    const u16* sp = ssb + (size_t)row * ldss;
    ushort4 sh = *(const ushort4*)(sp + shoff + lane * 4);
    ushort4 sc = *(const ushort4*)(sp + scoff + lane * 4);
    ushort4 o;
    o.x = f2b(n0 * (1.f + b2f(sc.x)) + b2f(sh.x));
    o.y = f2b(n1 * (1.f + b2f(sc.y)) + b2f(sh.y));
    o.z = f2b(n2 * (1.f + b2f(sc.z)) + b2f(sh.z));
    o.w = f2b(n3 * (1.f + b2f(sc.w)) + b2f(sh.w));
    ((ushort4*)(Y + (size_t)row * HID))[lane] = o;
}

// ---------------- attention ------------------------------------------------------------
// alpha only (no atomics): alpha[e,h] = sum_d q*k*ea / sqrt(32)
__global__ __launch_bounds__(256) void attn_alpha_k(
    const u16* __restrict__ qkv, const u16* __restrict__ ea, int lde,
    const int* __restrict__ src, const int* __restrict__ tgt,
    float* __restrict__ alpha)
{
    int e = blockIdx.x;
    int t = threadIdx.x;
    int h = t >> 5, d = t & 31;
    int s = src[e], g = tgt[e];
    float qv = b2f(qkv[(size_t)s * 768 + h * 32 + d]);
    float kv = b2f(qkv[(size_t)g * 768 + 256 + h * 32 + d]);
    float wv = b2f(ea[(size_t)e * lde + t]);
    float v = qv * kv * wv;
#pragma unroll
    for (int o = 16; o; o >>= 1) v += __shfl_xor(v, o, 32);
    if (d == 0) alpha[(size_t)e * 8 + h] = v * 0.17677669529663687f;  // 1/sqrt(32)
}

// ---------------- CSR build ------------------------------------------------------------
__global__ __launch_bounds__(256) void k_hist(
    const int* __restrict__ tgt, int* __restrict__ counts, int E)
{
    int i = blockIdx.x * 256 + threadIdx.x;
    if (i < E) atomicAdd(&counts[tgt[i]], 1);
}

// single block: exclusive scan of counts[0..Nn) -> offsets[0..Nn]
__global__ __launch_bounds__(256) void k_scan(
    const int* __restrict__ counts, int* __restrict__ offsets, int Nn)
{
    __shared__ int part[256];
    __shared__ int pref[257];
    int t = threadIdx.x;
    int chunk = (Nn + 255) / 256;
    int lo = t * chunk, hi = imin(lo + chunk, Nn);
    int s = 0;
    for (int i = lo; i < hi; ++i) s += counts[i];
    part[t] = s;
    __syncthreads();
    if (t == 0) {
        int run = 0;
        for (int i = 0; i < 256; ++i) { pref[i] = run; run += part[i]; }
        pref[256] = run;
        offsets[Nn] = run;
    }
    __syncthreads();
    int run = pref[t];
    for (int i = lo; i < hi; ++i) { offsets[i] = run; run += counts[i]; }
}

__global__ __launch_bounds__(256) void k_scatter(
    const int* __restrict__ tgt, int* __restrict__ cursor,
    int* __restrict__ eidlist, int E)
{
    int i = blockIdx.x * 256 + threadIdx.x;
    if (i < E) {
        int pos = atomicAdd(&cursor[tgt[i]], 1);
        eidlist[pos] = i;
    }
}

// per (node, head): amax and 1/sum(exp) over CSR edge list
__global__ __launch_bounds__(256) void k_amax_den(
    const float* __restrict__ alpha, const int* __restrict__ offsets,
    const int* __restrict__ eidlist, float* __restrict__ amaxF,
    float* __restrict__ invden, int NH8)
{
    int i = blockIdx.x * 256 + threadIdx.x;
    if (i >= NH8) return;
    int n = i >> 3, h = i & 7;
    int b = offsets[n], e = offsets[n + 1];
    float m = -1e30f;
    for (int k = b; k < e; ++k) m = fmaxf(m, alpha[(size_t)eidlist[k] * 8 + h]);
    float s = 0.f;
    for (int k = b; k < e; ++k) s += __expf(alpha[(size_t)eidlist[k] * 8 + h] - m);
    amaxF[i] = m;
    invden[i] = (s > 0.f) ? 1.f / s : 0.f;
}

// alpha[i] <- normalized softmax weight (streaming, no atomics)
__global__ __launch_bounds__(256) void k_norm(
    float* __restrict__ alpha, const float* __restrict__ amaxF,
    const float* __restrict__ invden, const int* __restrict__ tgt, int EH)
{
    int i = blockIdx.x * 256 + threadIdx.x;
    if (i >= EH) return;
    int e = i >> 3, h = i & 7;
    int g = tgt[e];
    alpha[i] = __expf(alpha[i] - amaxF[(size_t)g * 8 + h]) * invden[(size_t)g * 8 + h];
}

// message pass via CSR: hat[n,c] = V[n,c] * sum_{e in CSR[n]} e1[e,c]*w[e,h]
__global__ __launch_bounds__(256) void attn_msg_csr(
    const u16* __restrict__ qkv, const u16* __restrict__ ea1,
    const float* __restrict__ alpha, const int* __restrict__ offsets,
    const int* __restrict__ eidlist, float* __restrict__ hattn)
{
    int n = blockIdx.x;
    int c = threadIdx.x;
    int h = c >> 5;
    int b = offsets[n], e = offsets[n + 1];
    float acc = 0.f;
    for (int k = b; k < e; ++k) {
        int eid = eidlist[k];
        float w = alpha[(size_t)eid * 8 + h];
        acc += b2f(ea1[(size_t)eid * 512 + 256 + c]) * w;
    }
    hattn[(size_t)n * 256 + c] = b2f(qkv[(size_t)n * 768 + 512 + c]) * acc;
}

// ---------------- gsum -----------------------------------------------------------------
__global__ __launch_bounds__(256) void k_gsum_b16(
    const float* __restrict__ hattn, const int* __restrict__ src, const int* __restrict__ tgt,
    u16* __restrict__ g, long long cnt4)
{
    long long i = (long long)blockIdx.x * 256 + threadIdx.x;
    if (i >= cnt4) return;
    long long e = i >> 6;
    int c4 = (int)(i & 63) * 4;
    float4 a = *(const float4*)(hattn + (size_t)src[e] * 256 + c4);
    float4 b = *(const float4*)(hattn + (size_t)tgt[e] * 256 + c4);
    ushort4 o;
    o.x = f2b(a.x + b.x); o.y = f2b(a.y + b.y); o.z = f2b(a.z + b.z); o.w = f2b(a.w + b.w);
    ((ushort4*)g)[i] = o;
}

// ---------------------------------------------------------------------------------------
static inline void gemm(hipStream_t st, const u16* A, int lda, const u16* Bt, int ldb,
                        void* C, int ldc, int M, int N, int K,
                        const float* bias, int act, int obf16)
{
    dim3 g(N / 128, (M + 63) / 64);
    hipLaunchKernelGGL(gemm_mfma, g, dim3(256), 0, st, A, lda, Bt, ldb, C, ldc, M, N, K,
                       bias, act, obf16);
}

extern "C" void kernel_launch(void* const* d_in, const int* in_sizes, int n_in,
                              void* d_out, int out_size, void* d_ws, size_t ws_size,
                              hipStream_t stream)
{
    const int Nn = in_sizes[0];
    const int E = in_sizes[3] / HID;

    const float* x        = (const float*)d_in[1];
    const float* t_emb_h  = (const float*)d_in[2];
    const float* edge_attr= (const float*)d_in[3];
    const int*   eidx     = (const int*)d_in[4];
    const float* t_emb_e  = (const float*)d_in[5];
    const float* dist     = (const float*)d_in[6];
    const float* W_ee     = (const float*)d_in[7];
    const float* b_ee     = (const float*)d_in[8];
    const float* W_ad     = (const float*)d_in[9];
    const float* b_ad     = (const float*)d_in[10];
    const float* W_ade    = (const float*)d_in[11];
    const float* b_ade    = (const float*)d_in[12];
    const float* W_qkv    = (const float*)d_in[13];
    const float* W_e0     = (const float*)d_in[14];
    const float* W_e1     = (const float*)d_in[15];
    const float* W_n2e    = (const float*)d_in[16];
    const float* b_n2e    = (const float*)d_in[17];
    const float* g_ln     = (const float*)d_in[18];
    const float* b_ln     = (const float*)d_in[19];
    const float* W_f12    = (const float*)d_in[20];
    const float* W_fout   = (const float*)d_in[21];
    const float* W_fe12   = (const float*)d_in[22];
    const float* W_feout  = (const float*)d_in[23];

    const int* src = eidx;
    const int* tgt = eidx + E;

    float* outN = (float*)d_out;
    float* outE = (float*)d_out + (size_t)Nn * 256;

    // ---- persistent workspace ----
    char* W = (char*)d_ws;
    size_t off = 0;
    auto alloc = [&](size_t bytes) -> size_t {
        size_t o = off; off += (bytes + 255) & ~(size_t)255; return o;
    };
    float*    alpha = (float*)(W + alloc((size_t)E * 8 * 4));
    float*    amaxF = (float*)(W + alloc((size_t)Nn * 8 * 4));
    float*    invden= (float*)(W + alloc((size_t)Nn * 8 * 4));
    float*    hat   = (float*)(W + alloc((size_t)Nn * 256 * 4));
    int*      offs  = (int*)(W + alloc((size_t)(Nn + 1) * 4));
    int*      cursor= (int*)(W + alloc((size_t)Nn * 4));
    int*      eidl  = (int*)(W + alloc((size_t)E * 4));
    u16*      qkvb  = (u16*)(W + alloc((size_t)Nn * 768 * 2));
    u16*      sth   = (u16*)(W + alloc((size_t)Nn * 256 * 2));
    u16*      steb  = (u16*)(W + alloc((size_t)E * 256 * 2));    // silu(t_emb_e)
    u16*      eaeb  = (u16*)(W + alloc((size_t)E * 256 * 2));    // edge_attr_e (bf16)
    u16*      ea1b  = (u16*)(W + alloc((size_t)E * 512 * 2));    // [gelu(e_mod@W_e0) | e_mod@W_e1]
    u16*      adnb  = (u16*)(W + alloc((size_t)Nn * 1536 * 2));  // full node adaln
    u16*      xmb   = (u16*)(W + alloc((size_t)Nn * 256 * 2));
    u16*      h2nb  = (u16*)(W + alloc((size_t)Nn * 256 * 2));
    u16*      cnb   = (u16*)(W + alloc((size_t)Nn * 1024 * 2));
    // bf16 transposed weights (N x K)
    u16* weet   = (u16*)(W + alloc((size_t)256 * 384 * 2));
    u16* wadt   = (u16*)(W + alloc((size_t)1536 * 256 * 2));
    u16* wadet  = (u16*)(W + alloc((size_t)1536 * 256 * 2));
    u16* wqkvt  = (u16*)(W + alloc((size_t)768 * 256 * 2));
    u16* we01t  = (u16*)(W + alloc((size_t)512 * 256 * 2));      // [W_e0^T ; W_e1^T]
    u16* wn2et  = (u16*)(W + alloc((size_t)256 * 256 * 2));
    u16* wf12t  = (u16*)(W + alloc((size_t)2048 * 256 * 2));
    u16* wfoutt = (u16*)(W + alloc((size_t)256 * 1024 * 2));
    u16* wfe12t = (u16*)(W + alloc((size_t)2048 * 256 * 2));
    u16* wfeoutt= (u16*)(W + alloc((size_t)256 * 1024 * 2));

    char* pool = W + off;
    size_t poolB = (ws_size > off) ? (ws_size - off) : 0;
    auto chunkRowsB = [&](size_t bytesPerRow, int total) -> int {
        long c = (long)(poolB / bytesPerRow);
        c = (c / 256) * 256;
        if (c < 256) c = 256;
        if (c > total) c = (long)total;
        return (int)c;
    };

    // ---- CSR build by tgt (counts -> offsets -> eidlist) ----
    hipMemsetAsync(cursor, 0, (size_t)Nn * 4, stream);
    hipLaunchKernelGGL(k_hist, dim3((E + 255) / 256), dim3(256), 0, stream, tgt, cursor, E);
    hipLaunchKernelGGL(k_scan, dim3(1), dim3(256), 0, stream, cursor, offs, Nn);
    hipMemcpyAsync(cursor, offs, (size_t)Nn * 4, hipMemcpyDeviceToDevice, stream);
    hipLaunchKernelGGL(k_scatter, dim3((E + 255) / 256), dim3(256), 0, stream,
                       tgt, cursor, eidl, E);

    // ---- weight conversion ----
    {
        struct WC { const float* w; u16* wt; int K, N; } wl[] = {
            { W_ee,    weet,   384, 256 },
            { W_ad,    wadt,   256, 1536 },
            { W_ade,   wadet,  256, 1536 },
            { W_qkv,   wqkvt,  256, 768 },
            { W_e0,    we01t,  256, 256 },
            { W_e1,    we01t + 256 * 256, 256, 256 },
            { W_n2e,   wn2et,  256, 256 },
            { W_f12,   wf12t,  256, 2048 },
            { W_fout,  wfoutt, 1024, 256 },
            { W_fe12,  wfe12t, 256, 2048 },
            { W_feout, wfeoutt,1024, 256 },
        };
        for (auto& e : wl) {
            int cnt = e.K * e.N;
            hipLaunchKernelGGL(k_wconv, dim3((cnt + 255) / 256), dim3(256), 0, stream,
                               e.w, e.wt, e.K, e.N);
        }
    }

    // silu conversions (persistent)
    hipLaunchKernelGGL(k_silu_b16, dim3((unsigned)(((long long)Nn * 64 + 255) / 256)), dim3(256),
                       0, stream, t_emb_h, sth, (long long)Nn * 64);
    hipLaunchKernelGGL(k_silu_b16, dim3((unsigned)(((long long)E * 64 + 255) / 256)), dim3(256),
                       0, stream, t_emb_e, steb, (long long)E * 64);

    // ---- phase 1: node pre ----
    gemm(stream, sth, 256, wadt, 256, adnb, 1536, Nn, 1536, 256, b_ad, 0, 1);
    hipLaunchKernelGGL(k_ln_mod_b16, dim3((Nn + 3) / 4), dim3(256), 0, stream,
                       x, xmb, Nn, adnb, 1536, 0, 256);
    gemm(stream, xmb, 256, wqkvt, 256, qkvb, 768, Nn, 768, 256, nullptr, 0, 1);

    // ---- phase 2: edge pre ----
    {
        int C = chunkRowsB(1536 + 1024 + 512, E);
        char* p = pool;
        u16* eab2 = (u16*)p; p += (size_t)C * 1536;   // packed [edge_attr|dist] K=384 (bf16)
        u16* emsb = (u16*)p; p += (size_t)C * 1024;   // adaln_e[:,0:512) (bf16)
        u16* emod = (u16*)p;                          // C x 256 bf16
        for (int s = 0; s < E; s += C) {
            int cc = (E - s < C) ? (E - s) : C;
            hipLaunchKernelGGL(k_pack_ed, dim3((unsigned)(((long long)cc * 96 + 255) / 256)),
                               dim3(256), 0, stream, edge_attr + (size_t)s * 256,
                               dist + (size_t)s * 128, eab2, (long long)cc * 96);
            gemm(stream, eab2, 384, weet, 384, eaeb + (size_t)s * 256, 256, cc, 256, 384,
                 b_ee, 0, 1);
            gemm(stream, steb + (size_t)s * 256, 256, wadet, 256, emsb, 512, cc, 512, 256,
                 b_ade, 0, 1);
            hipLaunchKernelGGL(k_ln_mod_b16src, dim3((cc + 3) / 4), dim3(256), 0, stream,
                               eaeb + (size_t)s * 256, emod, cc, emsb, 512, 0, 256);
            gemm(stream, emod, 256, we01t, 256, ea1b + (size_t)s * 512, 512, cc, 512, 256,
                 nullptr, 4, 1);
            hipLaunchKernelGGL(attn_alpha_k, dim3(cc), dim3(256), 0, stream,
                               qkvb, ea1b + (size_t)s * 512, 512, src + s, tgt + s,
                               alpha + (size_t)s * 8);
        }
    }

    // ---- phase 3: softmax stats + normalize (no atomics) ----
    hipLaunchKernelGGL(k_amax_den, dim3((Nn * 8 + 255) / 256), dim3(256), 0, stream,
                       alpha, offs, eidl, amaxF, invden, Nn * 8);
    hipLaunchKernelGGL(k_norm, dim3((E * 8 + 255) / 256), dim3(256), 0, stream,
                       alpha, amaxF, invden, tgt, E * 8);

    // ---- phase 4: message pass via CSR (no atomics) ----
    hipLaunchKernelGGL(attn_msg_csr, dim3(Nn), dim3(256), 0, stream,
                       qkvb, ea1b, alpha, offs, eidl, hat);

    // ---- phase 5: node finish ----
    hipLaunchKernelGGL(k_ln_mod_resid_b16, dim3((Nn + 3) / 4), dim3(256), 0, stream,
                       x, hat, h2nb, Nn, adnb, 1536, 512, adnb, 1536, 768, 1024, g_ln, b_ln);
    hipLaunchKernelGGL(gemm_ffn12, dim3(16, (Nn + 63) / 64), dim3(256), 0, stream,
                       h2nb, wf12t, cnb, Nn);
    hipLaunchKernelGGL(gemm_out_final, dim3(2, (Nn + 63) / 64), dim3(256), 0, stream,
                       cnb, wfoutt, (const u16*)nullptr, h2nb, adnb, 1536, 1280, outN, Nn);

    // ---- phase 6: edge finish ----
    {
        int C = chunkRowsB(512 + 2048 + 1024 + 512 + 2048, E);
        char* p = pool;
        u16*   gsum = (u16*)p;  p += (size_t)C * 512;
        u16*   em2b = (u16*)p;  p += (size_t)C * 2048;   // adaln_e[:,512:1536)
        float* hep  = (float*)p; p += (size_t)C * 1024;
        u16*   h2e  = (u16*)p;  p += (size_t)C * 512;
        u16*   cne  = (u16*)p;                            // swiglu out C x 1024
        for (int s = 0; s < E; s += C) {
            int cc = (E - s < C) ? (E - s) : C;
            hipLaunchKernelGGL(k_gsum_b16, dim3((unsigned)(((long long)cc * 64 + 255) / 256)),
                               dim3(256), 0, stream, hat, src + s, tgt + s, gsum, (long long)cc * 64);
            gemm(stream, gsum, 256, wn2et, 256, hep, 256, cc, 256, 256, b_n2e, 0, 0);
            gemm(stream, steb + (size_t)s * 256, 256, wadet + 512 * 256, 256, em2b, 1024,
                 cc, 1024, 256, b_ade + 512, 0, 1);
            hipLaunchKernelGGL(k_ln_mod_resid_b16, dim3((cc + 3) / 4), dim3(256), 0, stream,
                               edge_attr + (size_t)s * 256, hep, h2e, cc,
                               em2b, 1024, 0, em2b, 1024, 256, 512, nullptr, nullptr);
            hipLaunchKernelGGL(gemm_ffn12, dim3(16, (cc + 63) / 64), dim3(256), 0, stream,
                               h2e, wfe12t, cne, cc);
            hipLaunchKernelGGL(gemm_out_final, dim3(2, (cc + 63) / 64), dim3(256), 0, stream,
                               cne, wfeoutt, eaeb + (size_t)s * 256, h2e,
                               em2b, 1024, 768, outE + (size_t)s * 256, cc);
        }
    }
    (void)n_in; (void)out_size;
}

// Round 15
// 2130.090 us; speedup vs baseline: 1.1004x; 1.0516x over previous
//
#include <hip/hip_runtime.h>

#define HID 256

typedef unsigned short u16;
typedef __attribute__((ext_vector_type(8))) short bf16x8;
typedef __attribute__((ext_vector_type(4))) float f32x4;

__device__ __forceinline__ float siluf(float x) { return x / (1.f + __expf(-x)); }
// tanh-approx gelu via sigmoid identity: 0.5x(1+tanh(z)) == x*sigmoid(2z)
__device__ __forceinline__ float geluf(float x) {
    return x / (1.f + __expf(-(1.59576912f * x + 0.07135481f * x * x * x)));
}
__device__ __forceinline__ u16 f2b(float x) {
    unsigned u = __float_as_uint(x);
    unsigned r = u + 0x7FFFu + ((u >> 16) & 1u);
    return (u16)(r >> 16);
}
__device__ __forceinline__ float b2f(u16 h) {
    return __uint_as_float(((unsigned)h) << 16);
}
__device__ __forceinline__ void gload16(const u16* g, u16* l) {
    __builtin_amdgcn_global_load_lds(
        (const __attribute__((address_space(1))) unsigned int*)g,
        (__attribute__((address_space(3))) unsigned int*)l, 16, 0, 0);
}
__device__ __forceinline__ int imin(int a, int b) { return a < b ? a : b; }

union B16x8 { u16 u[8]; uint4 q; };

// ---------------- bf16 MFMA GEMM: C = act(A @ Bt^T + bias) ------------------------------
// A: M x K bf16 (lda). Bt: N x K bf16 (ldb). 64x128 tile, BK=32, 4 waves 2x2 of 32x64.
// act: 1=silu, 2=gelu, 4=gelu on global cols [0,256) only. N%128==0, K%32==0.
__global__ __launch_bounds__(256) void gemm_mfma(
    const u16* __restrict__ A, int lda,
    const u16* __restrict__ Bt, int ldb,
    void* __restrict__ Cv, int ldc,
    int M, int N, int K,
    const float* __restrict__ bias, int act, int obf16)
{
    __shared__ u16 lds[8192];   // staging A(2048)+B(4096) u16; repack uses all 8192 u16

    const int tid  = threadIdx.x;
    const int lane = tid & 63;
    const int wave = tid >> 6;
    const int row0 = blockIdx.y * 64;
    const int col0 = blockIdx.x * 128;
    const int wm   = (wave >> 1) * 32;
    const int wn   = (wave & 1) * 64;

    f32x4 acc[2][4];
#pragma unroll
    for (int i = 0; i < 2; ++i)
#pragma unroll
        for (int j = 0; j < 4; ++j) acc[i][j] = (f32x4)0.0f;

    const int kc = (lane & 3) * 8;
    const int rr  = wave * 16 + (lane >> 2);
    const int rb1 = (wave + 4) * 16 + (lane >> 2);
    const u16* pa  = A + (size_t)imin(row0 + rr, M - 1) * lda + kc;
    const u16* pb0 = Bt + (size_t)(col0 + rr) * ldb + kc;
    const u16* pb1 = Bt + (size_t)(col0 + rb1) * ldb + kc;
    u16* la  = &lds[wave * 512];
    u16* lb0 = &lds[2048 + wave * 512];
    u16* lb1 = &lds[2048 + (wave + 4) * 512];

    const int kb = (lane >> 4) * 8;
    const int fr = lane & 15;

    for (int k0 = 0; k0 < K; k0 += 32) {
        gload16(pa + k0, la);
        gload16(pb0 + k0, lb0);
        gload16(pb1 + k0, lb1);
        __syncthreads();

        bf16x8 af[2], bfm[4];
#pragma unroll
        for (int i = 0; i < 2; ++i)
            af[i] = *(const bf16x8*)&lds[(wm + i * 16 + fr) * 32 + kb];
#pragma unroll
        for (int j = 0; j < 4; ++j)
            bfm[j] = *(const bf16x8*)&lds[2048 + (wn + j * 16 + fr) * 32 + kb];
#pragma unroll
        for (int i = 0; i < 2; ++i)
#pragma unroll
            for (int j = 0; j < 4; ++j)
                acc[i][j] = __builtin_amdgcn_mfma_f32_16x16x32_bf16(af[i], bfm[j], acc[i][j], 0, 0, 0);
        __syncthreads();
    }

    const int qr = (lane >> 4) * 4;
    if (obf16) {
#pragma unroll
        for (int i = 0; i < 2; ++i)
#pragma unroll
            for (int r = 0; r < 4; ++r)
#pragma unroll
                for (int j = 0; j < 4; ++j) {
                    int lcol = wn + j * 16 + fr;
                    int gcol = col0 + lcol;
                    float v = acc[i][j][r];
                    if (bias) v += bias[gcol];
                    if (act == 2) v = geluf(v);
                    else if (act == 1) v = siluf(v);
                    else if (act == 4 && gcol < 256) v = geluf(v);
                    lds[(wm + i * 16 + qr + r) * 128 + lcol] = f2b(v);
                }
        __syncthreads();
        int row = tid >> 2, cc0 = (tid & 3) * 32;   // 4 thr/row x 32 u16 = 128-wide row
        int grow = row0 + row;
        if (grow < M) {
            uint4* dst = (uint4*)((u16*)Cv + (size_t)grow * ldc + col0 + cc0);
            const uint4* sp = (const uint4*)&lds[row * 128 + cc0];
            dst[0] = sp[0]; dst[1] = sp[1]; dst[2] = sp[2]; dst[3] = sp[3];
        }
    } else {
        float* Cf = (float*)Cv;
#pragma unroll
        for (int i = 0; i < 2; ++i)
#pragma unroll
            for (int r = 0; r < 4; ++r) {
                int grow = row0 + wm + i * 16 + qr + r;
                if (grow >= M) continue;
#pragma unroll
                for (int j = 0; j < 4; ++j) {
                    int gcol = col0 + wn + j * 16 + fr;
                    float v = acc[i][j][r];
                    if (bias) v += bias[gcol];
                    if (act == 2) v = geluf(v);
                    else if (act == 1) v = siluf(v);
                    Cf[(size_t)grow * ldc + gcol] = v;
                }
            }
    }
}

// ------- gemm_cat: C(bf16) = [A1(fp32,256) | A2(fp32,128)] @ Bt^T + bias ----------------
// K=384, N=256 fixed. A reg-staged with fp32->bf16 convert. grid (2, ceil(M/64)).
__global__ __launch_bounds__(256) void gemm_cat(
    const float* __restrict__ A1, const float* __restrict__ A2,
    const u16* __restrict__ Bt,
    u16* __restrict__ C, int M, const float* __restrict__ bias)
{
    __shared__ u16 lds[8192];

    const int tid  = threadIdx.x;
    const int lane = tid & 63;
    const int wave = tid >> 6;
    const int row0 = blockIdx.y * 64;
    const int col0 = blockIdx.x * 128;
    const int wm   = (wave >> 1) * 32;
    const int wn   = (wave & 1) * 64;

    f32x4 acc[2][4];
#pragma unroll
    for (int i = 0; i < 2; ++i)
#pragma unroll
        for (int j = 0; j < 4; ++j) acc[i][j] = (f32x4)0.0f;

    const int kc = (lane & 3) * 8;
    const int rr  = wave * 16 + (lane >> 2);
    const int rb1 = (wave + 4) * 16 + (lane >> 2);
    const int gr  = imin(row0 + rr, M - 1);
    const u16* pb0 = Bt + (size_t)(col0 + rr) * 384 + kc;
    const u16* pb1 = Bt + (size_t)(col0 + rb1) * 384 + kc;
    u16* lb0 = &lds[2048 + wave * 512];
    u16* lb1 = &lds[2048 + (wave + 4) * 512];
    u16* laD = &lds[wave * 512 + (lane & 63) * 8];   // this lane's 8-u16 A slot

    const int kb = (lane >> 4) * 8;
    const int fr = lane & 15;

    for (int k0 = 0; k0 < 384; k0 += 32) {
        int kk = k0 + kc;
        const float* sp = (kk < 256) ? (A1 + (size_t)gr * 256 + kk)
                                     : (A2 + (size_t)gr * 128 + (kk - 256));
        float4 v0 = *(const float4*)sp;
        float4 v1 = *(const float4*)(sp + 4);
        gload16(pb0 + k0, lb0);
        gload16(pb1 + k0, lb1);
        B16x8 t;
        t.u[0] = f2b(v0.x); t.u[1] = f2b(v0.y); t.u[2] = f2b(v0.z); t.u[3] = f2b(v0.w);
        t.u[4] = f2b(v1.x); t.u[5] = f2b(v1.y); t.u[6] = f2b(v1.z); t.u[7] = f2b(v1.w);
        *(uint4*)laD = t.q;
        __syncthreads();

        bf16x8 af[2], bfm[4];
#pragma unroll
        for (int i = 0; i < 2; ++i)
            af[i] = *(const bf16x8*)&lds[(wm + i * 16 + fr) * 32 + kb];
#pragma unroll
        for (int j = 0; j < 4; ++j)
            bfm[j] = *(const bf16x8*)&lds[2048 + (wn + j * 16 + fr) * 32 + kb];
#pragma unroll
        for (int i = 0; i < 2; ++i)
#pragma unroll
            for (int j = 0; j < 4; ++j)
                acc[i][j] = __builtin_amdgcn_mfma_f32_16x16x32_bf16(af[i], bfm[j], acc[i][j], 0, 0, 0);
        __syncthreads();
    }

    const int qr = (lane >> 4) * 4;
#pragma unroll
    for (int i = 0; i < 2; ++i)
#pragma unroll
        for (int r = 0; r < 4; ++r)
#pragma unroll
            for (int j = 0; j < 4; ++j) {
                int lcol = wn + j * 16 + fr;
                float v = acc[i][j][r] + bias[col0 + lcol];
                lds[(wm + i * 16 + qr + r) * 128 + lcol] = f2b(v);
            }
    __syncthreads();
    int row = tid >> 2, cc0 = (tid & 3) * 32;
    int grow = row0 + row;
    if (grow < M) {
        uint4* dst = (uint4*)(C + (size_t)grow * 256 + col0 + cc0);
        const uint4* sp = (const uint4*)&lds[row * 128 + cc0];
        dst[0] = sp[0]; dst[1] = sp[1]; dst[2] = sp[2]; dst[3] = sp[3];
    }
}

// ------- gemm_gsum: C(bf16) = (hat[src]+hat[tgt]) @ Wn2e^T + b_n2e ----------------------
// K=256, N=256 fixed. A reg-staged gather-sum from hat (fp32). grid (2, ceil(M/64)).
__global__ __launch_bounds__(256) void gemm_gsum(
    const float* __restrict__ hat, const int* __restrict__ srcI, const int* __restrict__ tgtI,
    const u16* __restrict__ Bt,
    u16* __restrict__ C, int M, const float* __restrict__ bias)
{
    __shared__ u16 lds[8192];

    const int tid  = threadIdx.x;
    const int lane = tid & 63;
    const int wave = tid >> 6;
    const int row0 = blockIdx.y * 64;
    const int col0 = blockIdx.x * 128;
    const int wm   = (wave >> 1) * 32;
    const int wn   = (wave & 1) * 64;

    f32x4 acc[2][4];
#pragma unroll
    for (int i = 0; i < 2; ++i)
#pragma unroll
        for (int j = 0; j < 4; ++j) acc[i][j] = (f32x4)0.0f;

    const int kc = (lane & 3) * 8;
    const int rr  = wave * 16 + (lane >> 2);
    const int rb1 = (wave + 4) * 16 + (lane >> 2);
    const int gr  = imin(row0 + rr, M - 1);
    const float* ps = hat + (size_t)srcI[gr] * 256 + kc;
    const float* pt = hat + (size_t)tgtI[gr] * 256 + kc;
    const u16* pb0 = Bt + (size_t)(col0 + rr) * 256 + kc;
    const u16* pb1 = Bt + (size_t)(col0 + rb1) * 256 + kc;
    u16* lb0 = &lds[2048 + wave * 512];
    u16* lb1 = &lds[2048 + (wave + 4) * 512];
    u16* laD = &lds[wave * 512 + (lane & 63) * 8];

    const int kb = (lane >> 4) * 8;
    const int fr = lane & 15;

    for (int k0 = 0; k0 < 256; k0 += 32) {
        float4 a0 = *(const float4*)(ps + k0);
        float4 a1 = *(const float4*)(ps + k0 + 4);
        float4 b0 = *(const float4*)(pt + k0);
        float4 b1 = *(const float4*)(pt + k0 + 4);
        gload16(pb0 + k0, lb0);
        gload16(pb1 + k0, lb1);
        B16x8 t;
        t.u[0] = f2b(a0.x + b0.x); t.u[1] = f2b(a0.y + b0.y);
        t.u[2] = f2b(a0.z + b0.z); t.u[3] = f2b(a0.w + b0.w);
        t.u[4] = f2b(a1.x + b1.x); t.u[5] = f2b(a1.y + b1.y);
        t.u[6] = f2b(a1.z + b1.z); t.u[7] = f2b(a1.w + b1.w);
        *(uint4*)laD = t.q;
        __syncthreads();

        bf16x8 af[2], bfm[4];
#pragma unroll
        for (int i = 0; i < 2; ++i)
            af[i] = *(const bf16x8*)&lds[(wm + i * 16 + fr) * 32 + kb];
#pragma unroll
        for (int j = 0; j < 4; ++j)
            bfm[j] = *(const bf16x8*)&lds[2048 + (wn + j * 16 + fr) * 32 + kb];
#pragma unroll
        for (int i = 0; i < 2; ++i)
#pragma unroll
            for (int j = 0; j < 4; ++j)
                acc[i][j] = __builtin_amdgcn_mfma_f32_16x16x32_bf16(af[i], bfm[j], acc[i][j], 0, 0, 0);
        __syncthreads();
    }

    const int qr = (lane >> 4) * 4;
#pragma unroll
    for (int i = 0; i < 2; ++i)
#pragma unroll
        for (int r = 0; r < 4; ++r)
#pragma unroll
            for (int j = 0; j < 4; ++j) {
                int lcol = wn + j * 16 + fr;
                float v = acc[i][j][r] + bias[col0 + lcol];
                lds[(wm + i * 16 + qr + r) * 128 + lcol] = f2b(v);
            }
    __syncthreads();
    int row = tid >> 2, cc0 = (tid & 3) * 32;
    int grow = row0 + row;
    if (grow < M) {
        uint4* dst = (uint4*)(C + (size_t)grow * 256 + col0 + cc0);
        const uint4* sp = (const uint4*)&lds[row * 128 + cc0];
        dst[0] = sp[0]; dst[1] = sp[1]; dst[2] = sp[2]; dst[3] = sp[3];
    }
}

// ---------------- fused FFN12 + swiglu ---------------------------------------------------
__global__ __launch_bounds__(256) void gemm_ffn12(
    const u16* __restrict__ A, const u16* __restrict__ Wt,
    u16* __restrict__ C, int M)
{
    __shared__ u16 sm[6144];
    u16* lsA = sm;
    u16* lsB1 = sm + 2048;
    u16* lsB2 = sm + 4096;

    const int tid  = threadIdx.x;
    const int lane = tid & 63;
    const int wave = tid >> 6;
    const int row0 = blockIdx.y * 64;
    const int col0 = blockIdx.x * 64;
    const int wm   = (wave >> 1) * 32;
    const int wn   = (wave & 1) * 32;

    f32x4 accA[2][2], accB[2][2];
#pragma unroll
    for (int i = 0; i < 2; ++i)
#pragma unroll
        for (int j = 0; j < 2; ++j) { accA[i][j] = (f32x4)0.0f; accB[i][j] = (f32x4)0.0f; }

    const int kc = (lane & 3) * 8;
    const int rr = wave * 16 + (lane >> 2);
    const u16* pa  = A + (size_t)imin(row0 + rr, M - 1) * 256 + kc;
    const u16* pb1 = Wt + (size_t)(col0 + rr) * 256 + kc;
    const u16* pb2 = Wt + (size_t)(1024 + col0 + rr) * 256 + kc;
    u16* la  = &lsA[wave * 512];
    u16* lb1 = &lsB1[wave * 512];
    u16* lb2 = &lsB2[wave * 512];

    const int kb = (lane >> 4) * 8;
    const int fr = lane & 15;

#pragma unroll 1
    for (int k0 = 0; k0 < 256; k0 += 32) {
        gload16(pa + k0, la);
        gload16(pb1 + k0, lb1);
        gload16(pb2 + k0, lb2);
        __syncthreads();

        bf16x8 af[2], b1f[2], b2f_[2];
#pragma unroll
        for (int i = 0; i < 2; ++i)
            af[i] = *(const bf16x8*)&lsA[(wm + i * 16 + fr) * 32 + kb];
#pragma unroll
        for (int j = 0; j < 2; ++j) {
            b1f[j] = *(const bf16x8*)&lsB1[(wn + j * 16 + fr) * 32 + kb];
            b2f_[j] = *(const bf16x8*)&lsB2[(wn + j * 16 + fr) * 32 + kb];
        }
#pragma unroll
        for (int i = 0; i < 2; ++i)
#pragma unroll
            for (int j = 0; j < 2; ++j) {
                accA[i][j] = __builtin_amdgcn_mfma_f32_16x16x32_bf16(af[i], b1f[j], accA[i][j], 0, 0, 0);
                accB[i][j] = __builtin_amdgcn_mfma_f32_16x16x32_bf16(af[i], b2f_[j], accB[i][j], 0, 0, 0);
            }
        __syncthreads();
    }

    const int qr = (lane >> 4) * 4;
#pragma unroll
    for (int i = 0; i < 2; ++i)
#pragma unroll
        for (int r = 0; r < 4; ++r)
#pragma unroll
            for (int j = 0; j < 2; ++j) {
                float a = accA[i][j][r], b = accB[i][j][r];
                sm[(wm + i * 16 + qr + r) * 64 + wn + j * 16 + fr] = f2b(siluf(a) * b);
            }
    __syncthreads();
    int row = tid >> 2, cc0 = (tid & 3) * 16;
    int grow = row0 + row;
    if (grow < M) {
        uint4* dst = (uint4*)(C + (size_t)grow * 1024 + col0 + cc0);
        const uint4* sp = (const uint4*)&sm[row * 64 + cc0];
        dst[0] = sp[0]; dst[1] = sp[1];
    }
}

// ---------------- fused FFN-out + final: out = [eae(bf16) +] h2 + gate*(A@Wout) --------
__global__ __launch_bounds__(256) void gemm_out_final(
    const u16* __restrict__ A, const u16* __restrict__ Bt,
    const u16* __restrict__ eae, const u16* __restrict__ h2,
    const u16* __restrict__ gate, int ldg, int goff,
    float* __restrict__ out, int M)
{
    __shared__ u16 lds[6144];

    const int tid  = threadIdx.x;
    const int lane = tid & 63;
    const int wave = tid >> 6;
    const int row0 = blockIdx.y * 64;
    const int col0 = blockIdx.x * 128;
    const int wm   = (wave >> 1) * 32;
    const int wn   = (wave & 1) * 64;

    f32x4 acc[2][4];
#pragma unroll
    for (int i = 0; i < 2; ++i)
#pragma unroll
        for (int j = 0; j < 4; ++j) acc[i][j] = (f32x4)0.0f;

    const int kc = (lane & 3) * 8;
    const int rr = wave * 16 + (lane >> 2);
    const int rb1 = (wave + 4) * 16 + (lane >> 2);
    const u16* pa  = A + (size_t)imin(row0 + rr, M - 1) * 1024 + kc;
    const u16* pb0 = Bt + (size_t)(col0 + rr) * 1024 + kc;
    const u16* pb1 = Bt + (size_t)(col0 + rb1) * 1024 + kc;
    u16* la  = &lds[wave * 512];
    u16* lb0 = &lds[2048 + wave * 512];
    u16* lb1 = &lds[2048 + (wave + 4) * 512];

    const int kb = (lane >> 4) * 8;
    const int fr = lane & 15;

#pragma unroll 1
    for (int k0 = 0; k0 < 1024; k0 += 32) {
        gload16(pa + k0, la);
        gload16(pb0 + k0, lb0);
        gload16(pb1 + k0, lb1);
        __syncthreads();

        bf16x8 af[2], bfm[4];
#pragma unroll
        for (int i = 0; i < 2; ++i)
            af[i] = *(const bf16x8*)&lds[(wm + i * 16 + fr) * 32 + kb];
#pragma unroll
        for (int j = 0; j < 4; ++j)
            bfm[j] = *(const bf16x8*)&lds[2048 + (wn + j * 16 + fr) * 32 + kb];
#pragma unroll
        for (int i = 0; i < 2; ++i)
#pragma unroll
            for (int j = 0; j < 4; ++j)
                acc[i][j] = __builtin_amdgcn_mfma_f32_16x16x32_bf16(af[i], bfm[j], acc[i][j], 0, 0, 0);
        __syncthreads();
    }

    const int qr = (lane >> 4) * 4;
#pragma unroll
    for (int i = 0; i < 2; ++i)
#pragma unroll
        for (int r = 0; r < 4; ++r) {
            int grow = row0 + wm + i * 16 + qr + r;
            if (grow >= M) continue;
#pragma unroll
            for (int j = 0; j < 4; ++j) {
                int gcol = col0 + wn + j * 16 + fr;
                size_t idx = (size_t)grow * 256 + gcol;
                float v = acc[i][j][r] * b2f(gate[(size_t)grow * ldg + goff + gcol]) + b2f(h2[idx]);
                if (eae) v += b2f(eae[idx]);
                out[idx] = v;
            }
        }
}

// ---------------- weight transpose-convert ----------------------------------------------
__global__ __launch_bounds__(256) void k_wconv(
    const float* __restrict__ W, u16* __restrict__ Wt, int K, int N)
{
    int i = blockIdx.x * 256 + threadIdx.x;
    if (i >= K * N) return;
    int n = i / K, k = i - n * K;
    Wt[i] = f2b(W[(size_t)k * N + n]);
}

__global__ __launch_bounds__(256) void k_silu_b16(
    const float* __restrict__ src, u16* __restrict__ dst, long long n4)
{
    long long i = (long long)blockIdx.x * 256 + threadIdx.x;
    if (i >= n4) return;
    float4 v = ((const float4*)src)[i];
    ushort4 o;
    o.x = f2b(siluf(v.x)); o.y = f2b(siluf(v.y)); o.z = f2b(siluf(v.z)); o.w = f2b(siluf(v.w));
    ((ushort4*)dst)[i] = o;
}

// ---------------- LN + modulate (bf16 shift/scale) -> bf16, fp32 input ------------------
__global__ __launch_bounds__(256) void k_ln_mod_b16(
    const float* __restrict__ X, u16* __restrict__ Y, int M,
    const u16* __restrict__ ssb, int ldss, int shoff, int scoff)
{
    int row = (blockIdx.x << 2) + (threadIdx.x >> 6);
    if (row >= M) return;
    int lane = threadIdx.x & 63;
    const float* xr = X + (size_t)row * HID + lane * 4;
    float x0 = xr[0], x1 = xr[1], x2 = xr[2], x3 = xr[3];
    float s = x0 + x1 + x2 + x3;
    float q = x0 * x0 + x1 * x1 + x2 * x2 + x3 * x3;
#pragma unroll
    for (int o = 32; o; o >>= 1) { s += __shfl_xor(s, o, 64); q += __shfl_xor(q, o, 64); }
    float m = s * (1.f / HID);
    float r = rsqrtf(q * (1.f / HID) - m * m + 1e-6f);
    const u16* sp = ssb + (size_t)row * ldss;
    ushort4 sh = *(const ushort4*)(sp + shoff + lane * 4);
    ushort4 sc = *(const ushort4*)(sp + scoff + lane * 4);
    ushort4 o;
    o.x = f2b((x0 - m) * r * (1.f + b2f(sc.x)) + b2f(sh.x));
    o.y = f2b((x1 - m) * r * (1.f + b2f(sc.y)) + b2f(sh.y));
    o.z = f2b((x2 - m) * r * (1.f + b2f(sc.z)) + b2f(sh.z));
    o.w = f2b((x3 - m) * r * (1.f + b2f(sc.w)) + b2f(sh.w));
    ((ushort4*)(Y + (size_t)row * HID))[lane] = o;
}

// ---------------- LN + modulate, bf16 input variant -------------------------------------
__global__ __launch_bounds__(256) void k_ln_mod_b16src(
    const u16* __restrict__ X, u16* __restrict__ Y, int M,
    const u16* __restrict__ ssb, int ldss, int shoff, int scoff)
{
    int row = (blockIdx.x << 2) + (threadIdx.x >> 6);
    if (row >= M) return;
    int lane = threadIdx.x & 63;
    ushort4 xv = ((const ushort4*)(X + (size_t)row * HID))[lane];
    float x0 = b2f(xv.x), x1 = b2f(xv.y), x2 = b2f(xv.z), x3 = b2f(xv.w);
    float s = x0 + x1 + x2 + x3;
    float q = x0 * x0 + x1 * x1 + x2 * x2 + x3 * x3;
#pragma unroll
    for (int o = 32; o; o >>= 1) { s += __shfl_xor(s, o, 64); q += __shfl_xor(q, o, 64); }
    float m = s * (1.f / HID);
    float r = rsqrtf(q * (1.f / HID) - m * m + 1e-6f);
    const u16* sp = ssb + (size_t)row * ldss;
    ushort4 sh = *(const ushort4*)(sp + shoff + lane * 4);
    ushort4 sc = *(const ushort4*)(sp + scoff + lane * 4);
    ushort4 o;
    o.x = f2b((x0 - m) * r * (1.f + b2f(sc.x)) + b2f(sh.x));
    o.y = f2b((x1 - m) * r * (1.f + b2f(sc.y)) + b2f(sh.y));
    o.z = f2b((x2 - m) * r * (1.f + b2f(sc.z)) + b2f(sh.z));
    o.w = f2b((x3 - m) * r * (1.f + b2f(sc.w)) + b2f(sh.w));
    ((ushort4*)(Y + (size_t)row * HID))[lane] = o;
}

// ----- Y(bf16) = modulate( ln(A + gate.*Bv) [*g + b], shift, scale ); fp32 Bv -----------
__global__ __launch_bounds__(256) void k_ln_mod_resid_b16(
    const float* __restrict__ A, const float* __restrict__ Bv, u16* __restrict__ Y, int M,
    const u16* __restrict__ gb, int ldg, int goff,
    const u16* __restrict__ ssb, int ldss, int shoff, int scoff,
    const float* __restrict__ gw, const float* __restrict__ bw)
{
    int row = (blockIdx.x << 2) + (threadIdx.x >> 6);
    if (row >= M) return;
    int lane = threadIdx.x & 63;
    const float* ar = A + (size_t)row * HID + lane * 4;
    const float* br = Bv + (size_t)row * HID + lane * 4;
    ushort4 gp = *(const ushort4*)(gb + (size_t)row * ldg + goff + lane * 4);
    float t0 = ar[0] + b2f(gp.x) * br[0];
    float t1 = ar[1] + b2f(gp.y) * br[1];
    float t2 = ar[2] + b2f(gp.z) * br[2];
    float t3 = ar[3] + b2f(gp.w) * br[3];
    float s = t0 + t1 + t2 + t3;
    float q = t0 * t0 + t1 * t1 + t2 * t2 + t3 * t3;
#pragma unroll
    for (int o = 32; o; o >>= 1) { s += __shfl_xor(s, o, 64); q += __shfl_xor(q, o, 64); }
    float m = s * (1.f / HID);
    float r = rsqrtf(q * (1.f / HID) - m * m + 1e-6f);
    float n0 = (t0 - m) * r, n1 = (t1 - m) * r, n2 = (t2 - m) * r, n3 = (t3 - m) * r;
    if (gw) {
        const float* g4 = gw + lane * 4;
        const float* b4 = bw + lane * 4;
        n0 = n0 * g4[0] + b4[0]; n1 = n1 * g4[1] + b4[1];
        n2 = n2 * g4[2] + b4[2]; n3 = n3 * g4[3] + b4[3];
    }
    const u16* sp = ssb + (size_t)row * ldss;
    ushort4 sh = *(const ushort4*)(sp + shoff + lane * 4);
    ushort4 sc = *(const ushort4*)(sp + scoff + lane * 4);
    ushort4 o;
    o.x = f2b(n0 * (1.f + b2f(sc.x)) + b2f(sh.x));
    o.y = f2b(n1 * (1.f + b2f(sc.y)) + b2f(sh.y));
    o.z = f2b(n2 * (1.f + b2f(sc.z)) + b2f(sh.z));
    o.w = f2b(n3 * (1.f + b2f(sc.w)) + b2f(sh.w));
    ((ushort4*)(Y + (size_t)row * HID))[lane] = o;
}

// ----- same, but Bv is bf16 --------------------------------------------------------------
__global__ __launch_bounds__(256) void k_ln_mod_resid_b16bv(
    const float* __restrict__ A, const u16* __restrict__ Bv, u16* __restrict__ Y, int M,
    const u16* __restrict__ gb, int ldg, int goff,
    const u16* __restrict__ ssb, int ldss, int shoff, int scoff)
{
    int row = (blockIdx.x << 2) + (threadIdx.x >> 6);
    if (row >= M) return;
    int lane = threadIdx.x & 63;
    const float* ar = A + (size_t)row * HID + lane * 4;
    ushort4 bv = ((const ushort4*)(Bv + (size_t)row * HID))[lane];
    ushort4 gp = *(const ushort4*)(gb + (size_t)row * ldg + goff + lane * 4);
    float t0 = ar[0] + b2f(gp.x) * b2f(bv.x);
    float t1 = ar[1] + b2f(gp.y) * b2f(bv.y);
    float t2 = ar[2] + b2f(gp.z) * b2f(bv.z);
    float t3 = ar[3] + b2f(gp.w) * b2f(bv.w);
    float s = t0 + t1 + t2 + t3;
    float q = t0 * t0 + t1 * t1 + t2 * t2 + t3 * t3;
#pragma unroll
    for (int o = 32; o; o >>= 1) { s += __shfl_xor(s, o, 64); q += __shfl_xor(q, o, 64); }
    float m = s * (1.f / HID);
    float r = rsqrtf(q * (1.f / HID) - m * m + 1e-6f);
    float n0 = (t0 - m) * r, n1 = (t1 - m) * r, n2 = (t2 - m) * r, n3 = (t3 - m) * r;
    const u16* sp = ssb + (size_t)row * ldss;
    ushort4 sh = *(const ushort4*)(sp + shoff + lane * 4);
    ushort4 sc = *(const ushort4*)(sp + scoff + lane * 4);
    ushort4 o;
    o.x = f2b(n0 * (1.f + b2f(sc.x)) + b2f(sh.x));
    o.y = f2b(n1 * (1.f + b2f(sc.y)) + b2f(sh.y));
    o.z = f2b(n2 * (1.f + b2f(sc.z)) + b2f(sh.z));
    o.w = f2b(n3 * (1.f + b2f(sc.w)) + b2f(sh.w));
    ((ushort4*)(Y + (size_t)row * HID))[lane] = o;
}

// ---------------- attention ------------------------------------------------------------
__global__ __launch_bounds__(256) void attn_alpha_k(
    const u16* __restrict__ qkv, const u16* __restrict__ ea, int lde,
    const int* __restrict__ src, const int* __restrict__ tgt,
    float* __restrict__ alpha)
{
    int e = blockIdx.x;
    int t = threadIdx.x;
    int h = t >> 5, d = t & 31;
    int s = src[e], g = tgt[e];
    float qv = b2f(qkv[(size_t)s * 768 + h * 32 + d]);
    float kv = b2f(qkv[(size_t)g * 768 + 256 + h * 32 + d]);
    float wv = b2f(ea[(size_t)e * lde + t]);
    float v = qv * kv * wv;
#pragma unroll
    for (int o = 16; o; o >>= 1) v += __shfl_xor(v, o, 32);
    if (d == 0) alpha[(size_t)e * 8 + h] = v * 0.17677669529663687f;
}

// ---------------- CSR build ------------------------------------------------------------
__global__ __launch_bounds__(256) void k_hist(
    const int* __restrict__ tgt, int* __restrict__ counts, int E)
{
    int i = blockIdx.x * 256 + threadIdx.x;
    if (i < E) atomicAdd(&counts[tgt[i]], 1);
}

__global__ __launch_bounds__(256) void k_scan(
    const int* __restrict__ counts, int* __restrict__ offsets, int Nn)
{
    __shared__ int part[256];
    __shared__ int pref[257];
    int t = threadIdx.x;
    int chunk = (Nn + 255) / 256;
    int lo = t * chunk, hi = imin(lo + chunk, Nn);
    int s = 0;
    for (int i = lo; i < hi; ++i) s += counts[i];
    part[t] = s;
    __syncthreads();
    if (t == 0) {
        int run = 0;
        for (int i = 0; i < 256; ++i) { pref[i] = run; run += part[i]; }
        pref[256] = run;
        offsets[Nn] = run;
    }
    __syncthreads();
    int run = pref[t];
    for (int i = lo; i < hi; ++i) { offsets[i] = run; run += counts[i]; }
}

__global__ __launch_bounds__(256) void k_scatter(
    const int* __restrict__ tgt, int* __restrict__ cursor,
    int* __restrict__ eidlist, int E)
{
    int i = blockIdx.x * 256 + threadIdx.x;
    if (i < E) {
        int pos = atomicAdd(&cursor[tgt[i]], 1);
        eidlist[pos] = i;
    }
}

__global__ __launch_bounds__(256) void k_amax_den(
    const float* __restrict__ alpha, const int* __restrict__ offsets,
    const int* __restrict__ eidlist, float* __restrict__ amaxF,
    float* __restrict__ invden, int NH8)
{
    int i = blockIdx.x * 256 + threadIdx.x;
    if (i >= NH8) return;
    int n = i >> 3, h = i & 7;
    int b = offsets[n], e = offsets[n + 1];
    float m = -1e30f;
    for (int k = b; k < e; ++k) m = fmaxf(m, alpha[(size_t)eidlist[k] * 8 + h]);
    float s = 0.f;
    for (int k = b; k < e; ++k) s += __expf(alpha[(size_t)eidlist[k] * 8 + h] - m);
    amaxF[i] = m;
    invden[i] = (s > 0.f) ? 1.f / s : 0.f;
}

__global__ __launch_bounds__(256) void k_norm(
    float* __restrict__ alpha, const float* __restrict__ amaxF,
    const float* __restrict__ invden, const int* __restrict__ tgt, int EH)
{
    int i = blockIdx.x * 256 + threadIdx.x;
    if (i >= EH) return;
    int e = i >> 3, h = i & 7;
    int g = tgt[e];
    alpha[i] = __expf(alpha[i] - amaxF[(size_t)g * 8 + h]) * invden[(size_t)g * 8 + h];
}

__global__ __launch_bounds__(256) void attn_msg_csr(
    const u16* __restrict__ qkv, const u16* __restrict__ ea1,
    const float* __restrict__ alpha, const int* __restrict__ offsets,
    const int* __restrict__ eidlist, float* __restrict__ hattn)
{
    int n = blockIdx.x;
    int c = threadIdx.x;
    int h = c >> 5;
    int b = offsets[n], e = offsets[n + 1];
    float acc = 0.f;
    for (int k = b; k < e; ++k) {
        int eid = eidlist[k];
        float w = alpha[(size_t)eid * 8 + h];
        acc += b2f(ea1[(size_t)eid * 512 + 256 + c]) * w;
    }
    hattn[(size_t)n * 256 + c] = b2f(qkv[(size_t)n * 768 + 512 + c]) * acc;
}

// ---------------------------------------------------------------------------------------
static inline void gemm(hipStream_t st, const u16* A, int lda, const u16* Bt, int ldb,
                        void* C, int ldc, int M, int N, int K,
                        const float* bias, int act, int obf16)
{
    dim3 g(N / 128, (M + 63) / 64);
    hipLaunchKernelGGL(gemm_mfma, g, dim3(256), 0, st, A, lda, Bt, ldb, C, ldc, M, N, K,
                       bias, act, obf16);
}

extern "C" void kernel_launch(void* const* d_in, const int* in_sizes, int n_in,
                              void* d_out, int out_size, void* d_ws, size_t ws_size,
                              hipStream_t stream)
{
    const int Nn = in_sizes[0];
    const int E = in_sizes[3] / HID;

    const float* x        = (const float*)d_in[1];
    const float* t_emb_h  = (const float*)d_in[2];
    const float* edge_attr= (const float*)d_in[3];
    const int*   eidx     = (const int*)d_in[4];
    const float* t_emb_e  = (const float*)d_in[5];
    const float* dist     = (const float*)d_in[6];
    const float* W_ee     = (const float*)d_in[7];
    const float* b_ee     = (const float*)d_in[8];
    const float* W_ad     = (const float*)d_in[9];
    const float* b_ad     = (const float*)d_in[10];
    const float* W_ade    = (const float*)d_in[11];
    const float* b_ade    = (const float*)d_in[12];
    const float* W_qkv    = (const float*)d_in[13];
    const float* W_e0     = (const float*)d_in[14];
    const float* W_e1     = (const float*)d_in[15];
    const float* W_n2e    = (const float*)d_in[16];
    const float* b_n2e    = (const float*)d_in[17];
    const float* g_ln     = (const float*)d_in[18];
    const float* b_ln     = (const float*)d_in[19];
    const float* W_f12    = (const float*)d_in[20];
    const float* W_fout   = (const float*)d_in[21];
    const float* W_fe12   = (const float*)d_in[22];
    const float* W_feout  = (const float*)d_in[23];

    const int* src = eidx;
    const int* tgt = eidx + E;

    float* outN = (float*)d_out;
    float* outE = (float*)d_out + (size_t)Nn * 256;

    // ---- persistent workspace ----
    char* W = (char*)d_ws;
    size_t off = 0;
    auto alloc = [&](size_t bytes) -> size_t {
        size_t o = off; off += (bytes + 255) & ~(size_t)255; return o;
    };
    float*    alpha = (float*)(W + alloc((size_t)E * 8 * 4));
    float*    amaxF = (float*)(W + alloc((size_t)Nn * 8 * 4));
    float*    invden= (float*)(W + alloc((size_t)Nn * 8 * 4));
    float*    hat   = (float*)(W + alloc((size_t)Nn * 256 * 4));
    int*      offs  = (int*)(W + alloc((size_t)(Nn + 1) * 4));
    int*      cursor= (int*)(W + alloc((size_t)Nn * 4));
    int*      eidl  = (int*)(W + alloc((size_t)E * 4));
    u16*      qkvb  = (u16*)(W + alloc((size_t)Nn * 768 * 2));
    u16*      sth   = (u16*)(W + alloc((size_t)Nn * 256 * 2));
    u16*      steb  = (u16*)(W + alloc((size_t)E * 256 * 2));    // silu(t_emb_e)
    u16*      eaeb  = (u16*)(W + alloc((size_t)E * 256 * 2));    // edge_attr_e (bf16)
    u16*      ea1b  = (u16*)(W + alloc((size_t)E * 512 * 2));    // [gelu(e0) | e1]
    u16*      adnb  = (u16*)(W + alloc((size_t)Nn * 1536 * 2));
    u16*      xmb   = (u16*)(W + alloc((size_t)Nn * 256 * 2));
    u16*      h2nb  = (u16*)(W + alloc((size_t)Nn * 256 * 2));
    u16*      cnb   = (u16*)(W + alloc((size_t)Nn * 1024 * 2));
    // bf16 transposed weights (N x K)
    u16* weet   = (u16*)(W + alloc((size_t)256 * 384 * 2));
    u16* wadt   = (u16*)(W + alloc((size_t)1536 * 256 * 2));
    u16* wadet  = (u16*)(W + alloc((size_t)1536 * 256 * 2));
    u16* wqkvt  = (u16*)(W + alloc((size_t)768 * 256 * 2));
    u16* we01t  = (u16*)(W + alloc((size_t)512 * 256 * 2));
    u16* wn2et  = (u16*)(W + alloc((size_t)256 * 256 * 2));
    u16* wf12t  = (u16*)(W + alloc((size_t)2048 * 256 * 2));
    u16* wfoutt = (u16*)(W + alloc((size_t)256 * 1024 * 2));
    u16* wfe12t = (u16*)(W + alloc((size_t)2048 * 256 * 2));
    u16* wfeoutt= (u16*)(W + alloc((size_t)256 * 1024 * 2));

    char* pool = W + off;
    size_t poolB = (ws_size > off) ? (ws_size - off) : 0;
    auto chunkRowsB = [&](size_t bytesPerRow, int total) -> int {
        long c = (long)(poolB / bytesPerRow);
        c = (c / 256) * 256;
        if (c < 256) c = 256;
        if (c > total) c = (long)total;
        return (int)c;
    };

    // ---- CSR build by tgt ----
    hipMemsetAsync(cursor, 0, (size_t)Nn * 4, stream);
    hipLaunchKernelGGL(k_hist, dim3((E + 255) / 256), dim3(256), 0, stream, tgt, cursor, E);
    hipLaunchKernelGGL(k_scan, dim3(1), dim3(256), 0, stream, cursor, offs, Nn);
    hipMemcpyAsync(cursor, offs, (size_t)Nn * 4, hipMemcpyDeviceToDevice, stream);
    hipLaunchKernelGGL(k_scatter, dim3((E + 255) / 256), dim3(256), 0, stream,
                       tgt, cursor, eidl, E);

    // ---- weight conversion ----
    {
        struct WC { const float* w; u16* wt; int K, N; } wl[] = {
            { W_ee,    weet,   384, 256 },
            { W_ad,    wadt,   256, 1536 },
            { W_ade,   wadet,  256, 1536 },
            { W_qkv,   wqkvt,  256, 768 },
            { W_e0,    we01t,  256, 256 },
            { W_e1,    we01t + 256 * 256, 256, 256 },
            { W_n2e,   wn2et,  256, 256 },
            { W_f12,   wf12t,  256, 2048 },
            { W_fout,  wfoutt, 1024, 256 },
            { W_fe12,  wfe12t, 256, 2048 },
            { W_feout, wfeoutt,1024, 256 },
        };
        for (auto& e : wl) {
            int cnt = e.K * e.N;
            hipLaunchKernelGGL(k_wconv, dim3((cnt + 255) / 256), dim3(256), 0, stream,
                               e.w, e.wt, e.K, e.N);
        }
    }

    // silu conversions (persistent)
    hipLaunchKernelGGL(k_silu_b16, dim3((unsigned)(((long long)Nn * 64 + 255) / 256)), dim3(256),
                       0, stream, t_emb_h, sth, (long long)Nn * 64);
    hipLaunchKernelGGL(k_silu_b16, dim3((unsigned)(((long long)E * 64 + 255) / 256)), dim3(256),
                       0, stream, t_emb_e, steb, (long long)E * 64);

    // ---- phase 1: node pre ----
    gemm(stream, sth, 256, wadt, 256, adnb, 1536, Nn, 1536, 256, b_ad, 0, 1);
    hipLaunchKernelGGL(k_ln_mod_b16, dim3((Nn + 3) / 4), dim3(256), 0, stream,
                       x, xmb, Nn, adnb, 1536, 0, 256);
    gemm(stream, xmb, 256, wqkvt, 256, qkvb, 768, Nn, 768, 256, nullptr, 0, 1);

    // ---- phase 2: edge pre (cat-GEMM stages fp32 edge_attr|dist directly) ----
    {
        int C = chunkRowsB(1024 + 512, E);
        char* p = pool;
        u16* emsb = (u16*)p; p += (size_t)C * 1024;   // adaln_e[:,0:512) (bf16)
        u16* emod = (u16*)p;                          // C x 256 bf16
        for (int s = 0; s < E; s += C) {
            int cc = (E - s < C) ? (E - s) : C;
            hipLaunchKernelGGL(gemm_cat, dim3(2, (cc + 63) / 64), dim3(256), 0, stream,
                               edge_attr + (size_t)s * 256, dist + (size_t)s * 128,
                               weet, eaeb + (size_t)s * 256, cc, b_ee);
            gemm(stream, steb + (size_t)s * 256, 256, wadet, 256, emsb, 512, cc, 512, 256,
                 b_ade, 0, 1);
            hipLaunchKernelGGL(k_ln_mod_b16src, dim3((cc + 3) / 4), dim3(256), 0, stream,
                               eaeb + (size_t)s * 256, emod, cc, emsb, 512, 0, 256);
            gemm(stream, emod, 256, we01t, 256, ea1b + (size_t)s * 512, 512, cc, 512, 256,
                 nullptr, 4, 1);
            hipLaunchKernelGGL(attn_alpha_k, dim3(cc), dim3(256), 0, stream,
                               qkvb, ea1b + (size_t)s * 512, 512, src + s, tgt + s,
                               alpha + (size_t)s * 8);
        }
    }

    // ---- phase 3: softmax stats + normalize ----
    hipLaunchKernelGGL(k_amax_den, dim3((Nn * 8 + 255) / 256), dim3(256), 0, stream,
                       alpha, offs, eidl, amaxF, invden, Nn * 8);
    hipLaunchKernelGGL(k_norm, dim3((E * 8 + 255) / 256), dim3(256), 0, stream,
                       alpha, amaxF, invden, tgt, E * 8);

    // ---- phase 4: message pass via CSR ----
    hipLaunchKernelGGL(attn_msg_csr, dim3(Nn), dim3(256), 0, stream,
                       qkvb, ea1b, alpha, offs, eidl, hat);

    // ---- phase 5: node finish ----
    hipLaunchKernelGGL(k_ln_mod_resid_b16, dim3((Nn + 3) / 4), dim3(256), 0, stream,
                       x, hat, h2nb, Nn, adnb, 1536, 512, adnb, 1536, 768, 1024, g_ln, b_ln);
    hipLaunchKernelGGL(gemm_ffn12, dim3(16, (Nn + 63) / 64), dim3(256), 0, stream,
                       h2nb, wf12t, cnb, Nn);
    hipLaunchKernelGGL(gemm_out_final, dim3(2, (Nn + 63) / 64), dim3(256), 0, stream,
                       cnb, wfoutt, (const u16*)nullptr, h2nb, adnb, 1536, 1280, outN, Nn);

    // ---- phase 6: edge finish (gsum-GEMM gathers hat directly; hep bf16) ----
    {
        int C = chunkRowsB(2048 + 512 + 512 + 2048, E);
        char* p = pool;
        u16*   em2b = (u16*)p;  p += (size_t)C * 2048;   // adaln_e[:,512:1536)
        u16*   hep  = (u16*)p;  p += (size_t)C * 512;    // bf16
        u16*   h2e  = (u16*)p;  p += (size_t)C * 512;
        u16*   cne  = (u16*)p;                            // swiglu out C x 1024
        for (int s = 0; s < E; s += C) {
            int cc = (E - s < C) ? (E - s) : C;
            hipLaunchKernelGGL(gemm_gsum, dim3(2, (cc + 63) / 64), dim3(256), 0, stream,
                               hat, src + s, tgt + s, wn2et, hep, cc, b_n2e);
            gemm(stream, steb + (size_t)s * 256, 256, wadet + 512 * 256, 256, em2b, 1024,
                 cc, 1024, 256, b_ade + 512, 0, 1);
            hipLaunchKernelGGL(k_ln_mod_resid_b16bv, dim3((cc + 3) / 4), dim3(256), 0, stream,
                               edge_attr + (size_t)s * 256, hep, h2e, cc,
                               em2b, 1024, 0, em2b, 1024, 256, 512);
            hipLaunchKernelGGL(gemm_ffn12, dim3(16, (cc + 63) / 64), dim3(256), 0, stream,
                               h2e, wfe12t, cne, cc);
            hipLaunchKernelGGL(gemm_out_final, dim3(2, (cc + 63) / 64), dim3(256), 0, stream,
                               cne, wfeoutt, eaeb + (size_t)s * 256, h2e,
                               em2b, 1024, 768, outE + (size_t)s * 256, cc);
        }
    }
    (void)n_in; (void)out_size;
}

// Round 16
// 1894.974 us; speedup vs baseline: 1.2369x; 1.1241x over previous
//
#include <hip/hip_runtime.h>

#define HID 256

typedef unsigned short u16;
typedef __attribute__((ext_vector_type(8))) short bf16x8;
typedef __attribute__((ext_vector_type(4))) float f32x4;

__device__ __forceinline__ float siluf(float x) { return x / (1.f + __expf(-x)); }
// tanh-approx gelu via sigmoid identity: 0.5x(1+tanh(z)) == x*sigmoid(2z)
__device__ __forceinline__ float geluf(float x) {
    return x / (1.f + __expf(-(1.59576912f * x + 0.07135481f * x * x * x)));
}
__device__ __forceinline__ u16 f2b(float x) {
    unsigned u = __float_as_uint(x);
    unsigned r = u + 0x7FFFu + ((u >> 16) & 1u);
    return (u16)(r >> 16);
}
__device__ __forceinline__ float b2f(u16 h) {
    return __uint_as_float(((unsigned)h) << 16);
}
__device__ __forceinline__ void gload16(const u16* g, u16* l) {
    __builtin_amdgcn_global_load_lds(
        (const __attribute__((address_space(1))) unsigned int*)g,
        (__attribute__((address_space(3))) unsigned int*)l, 16, 0, 0);
}
__device__ __forceinline__ int imin(int a, int b) { return a < b ? a : b; }

union B16x8 { u16 u[8]; uint4 q; };

// ---------------- bf16 MFMA GEMM: C = act(A @ Bt^T + bias) ------------------------------
// A: M x K bf16 (lda). Bt: N x K bf16 (ldb). 64x128 tile, BK=32, 4 waves 2x2 of 32x64.
// act: 1=silu, 2=gelu. N%128==0, K%32==0.
__global__ __launch_bounds__(256) void gemm_mfma(
    const u16* __restrict__ A, int lda,
    const u16* __restrict__ Bt, int ldb,
    void* __restrict__ Cv, int ldc,
    int M, int N, int K,
    const float* __restrict__ bias, int act, int obf16)
{
    __shared__ u16 lds[8192];

    const int tid  = threadIdx.x;
    const int lane = tid & 63;
    const int wave = tid >> 6;
    const int row0 = blockIdx.y * 64;
    const int col0 = blockIdx.x * 128;
    const int wm   = (wave >> 1) * 32;
    const int wn   = (wave & 1) * 64;

    f32x4 acc[2][4];
#pragma unroll
    for (int i = 0; i < 2; ++i)
#pragma unroll
        for (int j = 0; j < 4; ++j) acc[i][j] = (f32x4)0.0f;

    const int kc = (lane & 3) * 8;
    const int rr  = wave * 16 + (lane >> 2);
    const int rb1 = (wave + 4) * 16 + (lane >> 2);
    const u16* pa  = A + (size_t)imin(row0 + rr, M - 1) * lda + kc;
    const u16* pb0 = Bt + (size_t)(col0 + rr) * ldb + kc;
    const u16* pb1 = Bt + (size_t)(col0 + rb1) * ldb + kc;
    u16* la  = &lds[wave * 512];
    u16* lb0 = &lds[2048 + wave * 512];
    u16* lb1 = &lds[2048 + (wave + 4) * 512];

    const int kb = (lane >> 4) * 8;
    const int fr = lane & 15;

    for (int k0 = 0; k0 < K; k0 += 32) {
        gload16(pa + k0, la);
        gload16(pb0 + k0, lb0);
        gload16(pb1 + k0, lb1);
        __syncthreads();

        bf16x8 af[2], bfm[4];
#pragma unroll
        for (int i = 0; i < 2; ++i)
            af[i] = *(const bf16x8*)&lds[(wm + i * 16 + fr) * 32 + kb];
#pragma unroll
        for (int j = 0; j < 4; ++j)
            bfm[j] = *(const bf16x8*)&lds[2048 + (wn + j * 16 + fr) * 32 + kb];
#pragma unroll
        for (int i = 0; i < 2; ++i)
#pragma unroll
            for (int j = 0; j < 4; ++j)
                acc[i][j] = __builtin_amdgcn_mfma_f32_16x16x32_bf16(af[i], bfm[j], acc[i][j], 0, 0, 0);
        __syncthreads();
    }

    const int qr = (lane >> 4) * 4;
    if (obf16) {
#pragma unroll
        for (int i = 0; i < 2; ++i)
#pragma unroll
            for (int r = 0; r < 4; ++r)
#pragma unroll
                for (int j = 0; j < 4; ++j) {
                    int lcol = wn + j * 16 + fr;
                    int gcol = col0 + lcol;
                    float v = acc[i][j][r];
                    if (bias) v += bias[gcol];
                    if (act == 2) v = geluf(v);
                    else if (act == 1) v = siluf(v);
                    lds[(wm + i * 16 + qr + r) * 128 + lcol] = f2b(v);
                }
        __syncthreads();
        int row = tid >> 2, cc0 = (tid & 3) * 32;
        int grow = row0 + row;
        if (grow < M) {
            uint4* dst = (uint4*)((u16*)Cv + (size_t)grow * ldc + col0 + cc0);
            const uint4* sp = (const uint4*)&lds[row * 128 + cc0];
            dst[0] = sp[0]; dst[1] = sp[1]; dst[2] = sp[2]; dst[3] = sp[3];
        }
    } else {
        float* Cf = (float*)Cv;
#pragma unroll
        for (int i = 0; i < 2; ++i)
#pragma unroll
            for (int r = 0; r < 4; ++r) {
                int grow = row0 + wm + i * 16 + qr + r;
                if (grow >= M) continue;
#pragma unroll
                for (int j = 0; j < 4; ++j) {
                    int gcol = col0 + wn + j * 16 + fr;
                    float v = acc[i][j][r];
                    if (bias) v += bias[gcol];
                    if (act == 2) v = geluf(v);
                    else if (act == 1) v = siluf(v);
                    Cf[(size_t)grow * ldc + gcol] = v;
                }
            }
    }
}

// ------- gemm_e01: fused [gelu(emod@We0)->alpha | emod@We1->e1b] ------------------------
// A: emod M x 256 bf16. Bt: we01t 512 x 256. grid (4, ceil(M/64)).
// bx<2: gelu cols (heads bx*4..bx*4+3) -> compute alpha[e,h] in-epilogue, NO global store.
// bx>=2: plain -> store to e1b (M x 256).
__global__ __launch_bounds__(256) void gemm_e01(
    const u16* __restrict__ A, const u16* __restrict__ Bt,
    u16* __restrict__ e1b, int M,
    const u16* __restrict__ qkv, const int* __restrict__ srcI, const int* __restrict__ tgtI,
    float* __restrict__ alpha)
{
    __shared__ u16 lds[8192];

    const int tid  = threadIdx.x;
    const int lane = tid & 63;
    const int wave = tid >> 6;
    const int row0 = blockIdx.y * 64;
    const int bx   = blockIdx.x;
    const int col0 = bx * 128;
    const int wm   = (wave >> 1) * 32;
    const int wn   = (wave & 1) * 64;

    f32x4 acc[2][4];
#pragma unroll
    for (int i = 0; i < 2; ++i)
#pragma unroll
        for (int j = 0; j < 4; ++j) acc[i][j] = (f32x4)0.0f;

    const int kc = (lane & 3) * 8;
    const int rr  = wave * 16 + (lane >> 2);
    const int rb1 = (wave + 4) * 16 + (lane >> 2);
    const u16* pa  = A + (size_t)imin(row0 + rr, M - 1) * 256 + kc;
    const u16* pb0 = Bt + (size_t)(col0 + rr) * 256 + kc;
    const u16* pb1 = Bt + (size_t)(col0 + rb1) * 256 + kc;
    u16* la  = &lds[wave * 512];
    u16* lb0 = &lds[2048 + wave * 512];
    u16* lb1 = &lds[2048 + (wave + 4) * 512];

    const int kb = (lane >> 4) * 8;
    const int fr = lane & 15;

    for (int k0 = 0; k0 < 256; k0 += 32) {
        gload16(pa + k0, la);
        gload16(pb0 + k0, lb0);
        gload16(pb1 + k0, lb1);
        __syncthreads();

        bf16x8 af[2], bfm[4];
#pragma unroll
        for (int i = 0; i < 2; ++i)
            af[i] = *(const bf16x8*)&lds[(wm + i * 16 + fr) * 32 + kb];
#pragma unroll
        for (int j = 0; j < 4; ++j)
            bfm[j] = *(const bf16x8*)&lds[2048 + (wn + j * 16 + fr) * 32 + kb];
#pragma unroll
        for (int i = 0; i < 2; ++i)
#pragma unroll
            for (int j = 0; j < 4; ++j)
                acc[i][j] = __builtin_amdgcn_mfma_f32_16x16x32_bf16(af[i], bfm[j], acc[i][j], 0, 0, 0);
        __syncthreads();
    }

    const int qr = (lane >> 4) * 4;
    const bool isE0 = (bx < 2);
#pragma unroll
    for (int i = 0; i < 2; ++i)
#pragma unroll
        for (int r = 0; r < 4; ++r)
#pragma unroll
            for (int j = 0; j < 4; ++j) {
                int lcol = wn + j * 16 + fr;
                float v = acc[i][j][r];
                if (isE0) v = geluf(v);
                lds[(wm + i * 16 + qr + r) * 128 + lcol] = f2b(v);
            }
    __syncthreads();
    int row = tid >> 2, cc0 = (tid & 3) * 32;
    int grow = row0 + row;
    if (grow < M) {
        if (isE0) {
            // alpha[e, head] = (1/sqrt(32)) * sum_c gelu_val * q[src,head*32+c] * k[tgt,head*32+c]
            int head = bx * 4 + (tid & 3);
            const u16* qv = qkv + (size_t)srcI[grow] * 768 + head * 32;
            const u16* kv = qkv + (size_t)tgtI[grow] * 768 + 256 + head * 32;
            const u16* gv = &lds[row * 128 + cc0];
            float s = 0.f;
#pragma unroll
            for (int c = 0; c < 32; ++c)
                s += b2f(gv[c]) * b2f(qv[c]) * b2f(kv[c]);
            alpha[(size_t)grow * 8 + head] = s * 0.17677669529663687f;
        } else {
            uint4* dst = (uint4*)(e1b + (size_t)grow * 256 + (col0 - 256) + cc0);
            const uint4* sp = (const uint4*)&lds[row * 128 + cc0];
            dst[0] = sp[0]; dst[1] = sp[1]; dst[2] = sp[2]; dst[3] = sp[3];
        }
    }
}

// ------- gemm_cat: C(bf16) = [A1(fp32,256) | A2(fp32,128)] @ Bt^T + bias ----------------
__global__ __launch_bounds__(256) void gemm_cat(
    const float* __restrict__ A1, const float* __restrict__ A2,
    const u16* __restrict__ Bt,
    u16* __restrict__ C, int M, const float* __restrict__ bias)
{
    __shared__ u16 lds[8192];

    const int tid  = threadIdx.x;
    const int lane = tid & 63;
    const int wave = tid >> 6;
    const int row0 = blockIdx.y * 64;
    const int col0 = blockIdx.x * 128;
    const int wm   = (wave >> 1) * 32;
    const int wn   = (wave & 1) * 64;

    f32x4 acc[2][4];
#pragma unroll
    for (int i = 0; i < 2; ++i)
#pragma unroll
        for (int j = 0; j < 4; ++j) acc[i][j] = (f32x4)0.0f;

    const int kc = (lane & 3) * 8;
    const int rr  = wave * 16 + (lane >> 2);
    const int rb1 = (wave + 4) * 16 + (lane >> 2);
    const int gr  = imin(row0 + rr, M - 1);
    const u16* pb0 = Bt + (size_t)(col0 + rr) * 384 + kc;
    const u16* pb1 = Bt + (size_t)(col0 + rb1) * 384 + kc;
    u16* lb0 = &lds[2048 + wave * 512];
    u16* lb1 = &lds[2048 + (wave + 4) * 512];
    u16* laD = &lds[wave * 512 + (lane & 63) * 8];

    const int kb = (lane >> 4) * 8;
    const int fr = lane & 15;

    for (int k0 = 0; k0 < 384; k0 += 32) {
        int kk = k0 + kc;
        const float* sp = (kk < 256) ? (A1 + (size_t)gr * 256 + kk)
                                     : (A2 + (size_t)gr * 128 + (kk - 256));
        float4 v0 = *(const float4*)sp;
        float4 v1 = *(const float4*)(sp + 4);
        gload16(pb0 + k0, lb0);
        gload16(pb1 + k0, lb1);
        B16x8 t;
        t.u[0] = f2b(v0.x); t.u[1] = f2b(v0.y); t.u[2] = f2b(v0.z); t.u[3] = f2b(v0.w);
        t.u[4] = f2b(v1.x); t.u[5] = f2b(v1.y); t.u[6] = f2b(v1.z); t.u[7] = f2b(v1.w);
        *(uint4*)laD = t.q;
        __syncthreads();

        bf16x8 af[2], bfm[4];
#pragma unroll
        for (int i = 0; i < 2; ++i)
            af[i] = *(const bf16x8*)&lds[(wm + i * 16 + fr) * 32 + kb];
#pragma unroll
        for (int j = 0; j < 4; ++j)
            bfm[j] = *(const bf16x8*)&lds[2048 + (wn + j * 16 + fr) * 32 + kb];
#pragma unroll
        for (int i = 0; i < 2; ++i)
#pragma unroll
            for (int j = 0; j < 4; ++j)
                acc[i][j] = __builtin_amdgcn_mfma_f32_16x16x32_bf16(af[i], bfm[j], acc[i][j], 0, 0, 0);
        __syncthreads();
    }

    const int qr = (lane >> 4) * 4;
#pragma unroll
    for (int i = 0; i < 2; ++i)
#pragma unroll
        for (int r = 0; r < 4; ++r)
#pragma unroll
            for (int j = 0; j < 4; ++j) {
                int lcol = wn + j * 16 + fr;
                float v = acc[i][j][r] + bias[col0 + lcol];
                lds[(wm + i * 16 + qr + r) * 128 + lcol] = f2b(v);
            }
    __syncthreads();
    int row = tid >> 2, cc0 = (tid & 3) * 32;
    int grow = row0 + row;
    if (grow < M) {
        uint4* dst = (uint4*)(C + (size_t)grow * 256 + col0 + cc0);
        const uint4* sp = (const uint4*)&lds[row * 128 + cc0];
        dst[0] = sp[0]; dst[1] = sp[1]; dst[2] = sp[2]; dst[3] = sp[3];
    }
}

// ------- gemm_gsum: C(bf16) = (hat[src]+hat[tgt]) @ Wn2e^T + b_n2e ----------------------
__global__ __launch_bounds__(256) void gemm_gsum(
    const float* __restrict__ hat, const int* __restrict__ srcI, const int* __restrict__ tgtI,
    const u16* __restrict__ Bt,
    u16* __restrict__ C, int M, const float* __restrict__ bias)
{
    __shared__ u16 lds[8192];

    const int tid  = threadIdx.x;
    const int lane = tid & 63;
    const int wave = tid >> 6;
    const int row0 = blockIdx.y * 64;
    const int col0 = blockIdx.x * 128;
    const int wm   = (wave >> 1) * 32;
    const int wn   = (wave & 1) * 64;

    f32x4 acc[2][4];
#pragma unroll
    for (int i = 0; i < 2; ++i)
#pragma unroll
        for (int j = 0; j < 4; ++j) acc[i][j] = (f32x4)0.0f;

    const int kc = (lane & 3) * 8;
    const int rr  = wave * 16 + (lane >> 2);
    const int rb1 = (wave + 4) * 16 + (lane >> 2);
    const int gr  = imin(row0 + rr, M - 1);
    const float* ps = hat + (size_t)srcI[gr] * 256 + kc;
    const float* pt = hat + (size_t)tgtI[gr] * 256 + kc;
    const u16* pb0 = Bt + (size_t)(col0 + rr) * 256 + kc;
    const u16* pb1 = Bt + (size_t)(col0 + rb1) * 256 + kc;
    u16* lb0 = &lds[2048 + wave * 512];
    u16* lb1 = &lds[2048 + (wave + 4) * 512];
    u16* laD = &lds[wave * 512 + (lane & 63) * 8];

    const int kb = (lane >> 4) * 8;
    const int fr = lane & 15;

    for (int k0 = 0; k0 < 256; k0 += 32) {
        float4 a0 = *(const float4*)(ps + k0);
        float4 a1 = *(const float4*)(ps + k0 + 4);
        float4 b0 = *(const float4*)(pt + k0);
        float4 b1 = *(const float4*)(pt + k0 + 4);
        gload16(pb0 + k0, lb0);
        gload16(pb1 + k0, lb1);
        B16x8 t;
        t.u[0] = f2b(a0.x + b0.x); t.u[1] = f2b(a0.y + b0.y);
        t.u[2] = f2b(a0.z + b0.z); t.u[3] = f2b(a0.w + b0.w);
        t.u[4] = f2b(a1.x + b1.x); t.u[5] = f2b(a1.y + b1.y);
        t.u[6] = f2b(a1.z + b1.z); t.u[7] = f2b(a1.w + b1.w);
        *(uint4*)laD = t.q;
        __syncthreads();

        bf16x8 af[2], bfm[4];
#pragma unroll
        for (int i = 0; i < 2; ++i)
            af[i] = *(const bf16x8*)&lds[(wm + i * 16 + fr) * 32 + kb];
#pragma unroll
        for (int j = 0; j < 4; ++j)
            bfm[j] = *(const bf16x8*)&lds[2048 + (wn + j * 16 + fr) * 32 + kb];
#pragma unroll
        for (int i = 0; i < 2; ++i)
#pragma unroll
            for (int j = 0; j < 4; ++j)
                acc[i][j] = __builtin_amdgcn_mfma_f32_16x16x32_bf16(af[i], bfm[j], acc[i][j], 0, 0, 0);
        __syncthreads();
    }

    const int qr = (lane >> 4) * 4;
#pragma unroll
    for (int i = 0; i < 2; ++i)
#pragma unroll
        for (int r = 0; r < 4; ++r)
#pragma unroll
            for (int j = 0; j < 4; ++j) {
                int lcol = wn + j * 16 + fr;
                float v = acc[i][j][r] + bias[col0 + lcol];
                lds[(wm + i * 16 + qr + r) * 128 + lcol] = f2b(v);
            }
    __syncthreads();
    int row = tid >> 2, cc0 = (tid & 3) * 32;
    int grow = row0 + row;
    if (grow < M) {
        uint4* dst = (uint4*)(C + (size_t)grow * 256 + col0 + cc0);
        const uint4* sp = (const uint4*)&lds[row * 128 + cc0];
        dst[0] = sp[0]; dst[1] = sp[1]; dst[2] = sp[2]; dst[3] = sp[3];
    }
}

// ---------------- fused FFN12 + swiglu ---------------------------------------------------
__global__ __launch_bounds__(256) void gemm_ffn12(
    const u16* __restrict__ A, const u16* __restrict__ Wt,
    u16* __restrict__ C, int M)
{
    __shared__ u16 sm[6144];
    u16* lsA = sm;
    u16* lsB1 = sm + 2048;
    u16* lsB2 = sm + 4096;

    const int tid  = threadIdx.x;
    const int lane = tid & 63;
    const int wave = tid >> 6;
    const int row0 = blockIdx.y * 64;
    const int col0 = blockIdx.x * 64;
    const int wm   = (wave >> 1) * 32;
    const int wn   = (wave & 1) * 32;

    f32x4 accA[2][2], accB[2][2];
#pragma unroll
    for (int i = 0; i < 2; ++i)
#pragma unroll
        for (int j = 0; j < 2; ++j) { accA[i][j] = (f32x4)0.0f; accB[i][j] = (f32x4)0.0f; }

    const int kc = (lane & 3) * 8;
    const int rr = wave * 16 + (lane >> 2);
    const u16* pa  = A + (size_t)imin(row0 + rr, M - 1) * 256 + kc;
    const u16* pb1 = Wt + (size_t)(col0 + rr) * 256 + kc;
    const u16* pb2 = Wt + (size_t)(1024 + col0 + rr) * 256 + kc;
    u16* la  = &lsA[wave * 512];
    u16* lb1 = &lsB1[wave * 512];
    u16* lb2 = &lsB2[wave * 512];

    const int kb = (lane >> 4) * 8;
    const int fr = lane & 15;

#pragma unroll 1
    for (int k0 = 0; k0 < 256; k0 += 32) {
        gload16(pa + k0, la);
        gload16(pb1 + k0, lb1);
        gload16(pb2 + k0, lb2);
        __syncthreads();

        bf16x8 af[2], b1f[2], b2f_[2];
#pragma unroll
        for (int i = 0; i < 2; ++i)
            af[i] = *(const bf16x8*)&lsA[(wm + i * 16 + fr) * 32 + kb];
#pragma unroll
        for (int j = 0; j < 2; ++j) {
            b1f[j] = *(const bf16x8*)&lsB1[(wn + j * 16 + fr) * 32 + kb];
            b2f_[j] = *(const bf16x8*)&lsB2[(wn + j * 16 + fr) * 32 + kb];
        }
#pragma unroll
        for (int i = 0; i < 2; ++i)
#pragma unroll
            for (int j = 0; j < 2; ++j) {
                accA[i][j] = __builtin_amdgcn_mfma_f32_16x16x32_bf16(af[i], b1f[j], accA[i][j], 0, 0, 0);
                accB[i][j] = __builtin_amdgcn_mfma_f32_16x16x32_bf16(af[i], b2f_[j], accB[i][j], 0, 0, 0);
            }
        __syncthreads();
    }

    const int qr = (lane >> 4) * 4;
#pragma unroll
    for (int i = 0; i < 2; ++i)
#pragma unroll
        for (int r = 0; r < 4; ++r)
#pragma unroll
            for (int j = 0; j < 2; ++j) {
                float a = accA[i][j][r], b = accB[i][j][r];
                sm[(wm + i * 16 + qr + r) * 64 + wn + j * 16 + fr] = f2b(siluf(a) * b);
            }
    __syncthreads();
    int row = tid >> 2, cc0 = (tid & 3) * 16;
    int grow = row0 + row;
    if (grow < M) {
        uint4* dst = (uint4*)(C + (size_t)grow * 1024 + col0 + cc0);
        const uint4* sp = (const uint4*)&sm[row * 64 + cc0];
        dst[0] = sp[0]; dst[1] = sp[1];
    }
}

// ---------------- fused FFN-out + final: out = [eae(bf16) +] h2 + gate*(A@Wout) --------
__global__ __launch_bounds__(256) void gemm_out_final(
    const u16* __restrict__ A, const u16* __restrict__ Bt,
    const u16* __restrict__ eae, const u16* __restrict__ h2,
    const u16* __restrict__ gate, int ldg, int goff,
    float* __restrict__ out, int M)
{
    __shared__ u16 lds[6144];

    const int tid  = threadIdx.x;
    const int lane = tid & 63;
    const int wave = tid >> 6;
    const int row0 = blockIdx.y * 64;
    const int col0 = blockIdx.x * 128;
    const int wm   = (wave >> 1) * 32;
    const int wn   = (wave & 1) * 64;

    f32x4 acc[2][4];
#pragma unroll
    for (int i = 0; i < 2; ++i)
#pragma unroll
        for (int j = 0; j < 4; ++j) acc[i][j] = (f32x4)0.0f;

    const int kc = (lane & 3) * 8;
    const int rr = wave * 16 + (lane >> 2);
    const int rb1 = (wave + 4) * 16 + (lane >> 2);
    const u16* pa  = A + (size_t)imin(row0 + rr, M - 1) * 1024 + kc;
    const u16* pb0 = Bt + (size_t)(col0 + rr) * 1024 + kc;
    const u16* pb1 = Bt + (size_t)(col0 + rb1) * 1024 + kc;
    u16* la  = &lds[wave * 512];
    u16* lb0 = &lds[2048 + wave * 512];
    u16* lb1 = &lds[2048 + (wave + 4) * 512];

    const int kb = (lane >> 4) * 8;
    const int fr = lane & 15;

#pragma unroll 1
    for (int k0 = 0; k0 < 1024; k0 += 32) {
        gload16(pa + k0, la);
        gload16(pb0 + k0, lb0);
        gload16(pb1 + k0, lb1);
        __syncthreads();

        bf16x8 af[2], bfm[4];
#pragma unroll
        for (int i = 0; i < 2; ++i)
            af[i] = *(const bf16x8*)&lds[(wm + i * 16 + fr) * 32 + kb];
#pragma unroll
        for (int j = 0; j < 4; ++j)
            bfm[j] = *(const bf16x8*)&lds[2048 + (wn + j * 16 + fr) * 32 + kb];
#pragma unroll
        for (int i = 0; i < 2; ++i)
#pragma unroll
            for (int j = 0; j < 4; ++j)
                acc[i][j] = __builtin_amdgcn_mfma_f32_16x16x32_bf16(af[i], bfm[j], acc[i][j], 0, 0, 0);
        __syncthreads();
    }

    const int qr = (lane >> 4) * 4;
#pragma unroll
    for (int i = 0; i < 2; ++i)
#pragma unroll
        for (int r = 0; r < 4; ++r) {
            int grow = row0 + wm + i * 16 + qr + r;
            if (grow >= M) continue;
#pragma unroll
            for (int j = 0; j < 4; ++j) {
                int gcol = col0 + wn + j * 16 + fr;
                size_t idx = (size_t)grow * 256 + gcol;
                float v = acc[i][j][r] * b2f(gate[(size_t)grow * ldg + goff + gcol]) + b2f(h2[idx]);
                if (eae) v += b2f(eae[idx]);
                out[idx] = v;
            }
        }
}

// ---------------- weight transpose-convert ----------------------------------------------
__global__ __launch_bounds__(256) void k_wconv(
    const float* __restrict__ W, u16* __restrict__ Wt, int K, int N)
{
    int i = blockIdx.x * 256 + threadIdx.x;
    if (i >= K * N) return;
    int n = i / K, k = i - n * K;
    Wt[i] = f2b(W[(size_t)k * N + n]);
}

__global__ __launch_bounds__(256) void k_silu_b16(
    const float* __restrict__ src, u16* __restrict__ dst, long long n4)
{
    long long i = (long long)blockIdx.x * 256 + threadIdx.x;
    if (i >= n4) return;
    float4 v = ((const float4*)src)[i];
    ushort4 o;
    o.x = f2b(siluf(v.x)); o.y = f2b(siluf(v.y)); o.z = f2b(siluf(v.z)); o.w = f2b(siluf(v.w));
    ((ushort4*)dst)[i] = o;
}

// ---------------- LN + modulate (bf16 shift/scale) -> bf16, fp32 input ------------------
__global__ __launch_bounds__(256) void k_ln_mod_b16(
    const float* __restrict__ X, u16* __restrict__ Y, int M,
    const u16* __restrict__ ssb, int ldss, int shoff, int scoff)
{
    int row = (blockIdx.x << 2) + (threadIdx.x >> 6);
    if (row >= M) return;
    int lane = threadIdx.x & 63;
    const float* xr = X + (size_t)row * HID + lane * 4;
    float x0 = xr[0], x1 = xr[1], x2 = xr[2], x3 = xr[3];
    float s = x0 + x1 + x2 + x3;
    float q = x0 * x0 + x1 * x1 + x2 * x2 + x3 * x3;
#pragma unroll
    for (int o = 32; o; o >>= 1) { s += __shfl_xor(s, o, 64); q += __shfl_xor(q, o, 64); }
    float m = s * (1.f / HID);
    float r = rsqrtf(q * (1.f / HID) - m * m + 1e-6f);
    const u16* sp = ssb + (size_t)row * ldss;
    ushort4 sh = *(const ushort4*)(sp + shoff + lane * 4);
    ushort4 sc = *(const ushort4*)(sp + scoff + lane * 4);
    ushort4 o;
    o.x = f2b((x0 - m) * r * (1.f + b2f(sc.x)) + b2f(sh.x));
    o.y = f2b((x1 - m) * r * (1.f + b2f(sc.y)) + b2f(sh.y));
    o.z = f2b((x2 - m) * r * (1.f + b2f(sc.z)) + b2f(sh.z));
    o.w = f2b((x3 - m) * r * (1.f + b2f(sc.w)) + b2f(sh.w));
    ((ushort4*)(Y + (size_t)row * HID))[lane] = o;
}

// ---------------- LN + modulate, bf16 input variant -------------------------------------
__global__ __launch_bounds__(256) void k_ln_mod_b16src(
    const u16* __restrict__ X, u16* __restrict__ Y, int M,
    const u16* __restrict__ ssb, int ldss, int shoff, int scoff)
{
    int row = (blockIdx.x << 2) + (threadIdx.x >> 6);
    if (row >= M) return;
    int lane = threadIdx.x & 63;
    ushort4 xv = ((const ushort4*)(X + (size_t)row * HID))[lane];
    float x0 = b2f(xv.x), x1 = b2f(xv.y), x2 = b2f(xv.z), x3 = b2f(xv.w);
    float s = x0 + x1 + x2 + x3;
    float q = x0 * x0 + x1 * x1 + x2 * x2 + x3 * x3;
#pragma unroll
    for (int o = 32; o; o >>= 1) { s += __shfl_xor(s, o, 64); q += __shfl_xor(q, o, 64); }
    float m = s * (1.f / HID);
    float r = rsqrtf(q * (1.f / HID) - m * m + 1e-6f);
    const u16* sp = ssb + (size_t)row * ldss;
    ushort4 sh = *(const ushort4*)(sp + shoff + lane * 4);
    ushort4 sc = *(const ushort4*)(sp + scoff + lane * 4);
    ushort4 o;
    o.x = f2b((x0 - m) * r * (1.f + b2f(sc.x)) + b2f(sh.x));
    o.y = f2b((x1 - m) * r * (1.f + b2f(sc.y)) + b2f(sh.y));
    o.z = f2b((x2 - m) * r * (1.f + b2f(sc.z)) + b2f(sh.z));
    o.w = f2b((x3 - m) * r * (1.f + b2f(sc.w)) + b2f(sh.w));
    ((ushort4*)(Y + (size_t)row * HID))[lane] = o;
}

// ----- Y(bf16) = modulate( ln(A + gate.*Bv) [*g + b], shift, scale ); fp32 Bv -----------
__global__ __launch_bounds__(256) void k_ln_mod_resid_b16(
    const float* __restrict__ A, const float* __restrict__ Bv, u16* __restrict__ Y, int M,
    const u16* __restrict__ gb, int ldg, int goff,
    const u16* __restrict__ ssb, int ldss, int shoff, int scoff,
    const float* __restrict__ gw, const float* __restrict__ bw)
{
    int row = (blockIdx.x << 2) + (threadIdx.x >> 6);
    if (row >= M) return;
    int lane = threadIdx.x & 63;
    const float* ar = A + (size_t)row * HID + lane * 4;
    const float* br = Bv + (size_t)row * HID + lane * 4;
    ushort4 gp = *(const ushort4*)(gb + (size_t)row * ldg + goff + lane * 4);
    float t0 = ar[0] + b2f(gp.x) * br[0];
    float t1 = ar[1] + b2f(gp.y) * br[1];
    float t2 = ar[2] + b2f(gp.z) * br[2];
    float t3 = ar[3] + b2f(gp.w) * br[3];
    float s = t0 + t1 + t2 + t3;
    float q = t0 * t0 + t1 * t1 + t2 * t2 + t3 * t3;
#pragma unroll
    for (int o = 32; o; o >>= 1) { s += __shfl_xor(s, o, 64); q += __shfl_xor(q, o, 64); }
    float m = s * (1.f / HID);
    float r = rsqrtf(q * (1.f / HID) - m * m + 1e-6f);
    float n0 = (t0 - m) * r, n1 = (t1 - m) * r, n2 = (t2 - m) * r, n3 = (t3 - m) * r;
    if (gw) {
        const float* g4 = gw + lane * 4;
        const float* b4 = bw + lane * 4;
        n0 = n0 * g4[0] + b4[0]; n1 = n1 * g4[1] + b4[1];
        n2 = n2 * g4[2] + b4[2]; n3 = n3 * g4[3] + b4[3];
    }
    const u16* sp = ssb + (size_t)row * ldss;
    ushort4 sh = *(const ushort4*)(sp + shoff + lane * 4);
    ushort4 sc = *(const ushort4*)(sp + scoff + lane * 4);
    ushort4 o;
    o.x = f2b(n0 * (1.f + b2f(sc.x)) + b2f(sh.x));
    o.y = f2b(n1 * (1.f + b2f(sc.y)) + b2f(sh.y));
    o.z = f2b(n2 * (1.f + b2f(sc.z)) + b2f(sh.z));
    o.w = f2b(n3 * (1.f + b2f(sc.w)) + b2f(sh.w));
    ((ushort4*)(Y + (size_t)row * HID))[lane] = o;
}

// ----- same, but Bv is bf16 --------------------------------------------------------------
__global__ __launch_bounds__(256) void k_ln_mod_resid_b16bv(
    const float* __restrict__ A, const u16* __restrict__ Bv, u16* __restrict__ Y, int M,
    const u16* __restrict__ gb, int ldg, int goff,
    const u16* __restrict__ ssb, int ldss, int shoff, int scoff)
{
    int row = (blockIdx.x << 2) + (threadIdx.x >> 6);
    if (row >= M) return;
    int lane = threadIdx.x & 63;
    const float* ar = A + (size_t)row * HID + lane * 4;
    ushort4 bv = ((const ushort4*)(Bv + (size_t)row * HID))[lane];
    ushort4 gp = *(const ushort4*)(gb + (size_t)row * ldg + goff + lane * 4);
    float t0 = ar[0] + b2f(gp.x) * b2f(bv.x);
    float t1 = ar[1] + b2f(gp.y) * b2f(bv.y);
    float t2 = ar[2] + b2f(gp.z) * b2f(bv.z);
    float t3 = ar[3] + b2f(gp.w) * b2f(bv.w);
    float s = t0 + t1 + t2 + t3;
    float q = t0 * t0 + t1 * t1 + t2 * t2 + t3 * t3;
#pragma unroll
    for (int o = 32; o; o >>= 1) { s += __shfl_xor(s, o, 64); q += __shfl_xor(q, o, 64); }
    float m = s * (1.f / HID);
    float r = rsqrtf(q * (1.f / HID) - m * m + 1e-6f);
    float n0 = (t0 - m) * r, n1 = (t1 - m) * r, n2 = (t2 - m) * r, n3 = (t3 - m) * r;
    const u16* sp = ssb + (size_t)row * ldss;
    ushort4 sh = *(const ushort4*)(sp + shoff + lane * 4);
    ushort4 sc = *(const ushort4*)(sp + scoff + lane * 4);
    ushort4 o;
    o.x = f2b(n0 * (1.f + b2f(sc.x)) + b2f(sh.x));
    o.y = f2b(n1 * (1.f + b2f(sc.y)) + b2f(sh.y));
    o.z = f2b(n2 * (1.f + b2f(sc.z)) + b2f(sh.z));
    o.w = f2b(n3 * (1.f + b2f(sc.w)) + b2f(sh.w));
    ((ushort4*)(Y + (size_t)row * HID))[lane] = o;
}

// ---------------- CSR build ------------------------------------------------------------
__global__ __launch_bounds__(256) void k_hist(
    const int* __restrict__ tgt, int* __restrict__ counts, int E)
{
    int i = blockIdx.x * 256 + threadIdx.x;
    if (i < E) atomicAdd(&counts[tgt[i]], 1);
}

__global__ __launch_bounds__(256) void k_scan(
    const int* __restrict__ counts, int* __restrict__ offsets, int Nn)
{
    __shared__ int part[256];
    __shared__ int pref[257];
    int t = threadIdx.x;
    int chunk = (Nn + 255) / 256;
    int lo = t * chunk, hi = imin(lo + chunk, Nn);
    int s = 0;
    for (int i = lo; i < hi; ++i) s += counts[i];
    part[t] = s;
    __syncthreads();
    if (t == 0) {
        int run = 0;
        for (int i = 0; i < 256; ++i) { pref[i] = run; run += part[i]; }
        pref[256] = run;
        offsets[Nn] = run;
    }
    __syncthreads();
    int run = pref[t];
    for (int i = lo; i < hi; ++i) { offsets[i] = run; run += counts[i]; }
}

__global__ __launch_bounds__(256) void k_scatter(
    const int* __restrict__ tgt, int* __restrict__ cursor,
    int* __restrict__ eidlist, int E)
{
    int i = blockIdx.x * 256 + threadIdx.x;
    if (i < E) {
        int pos = atomicAdd(&cursor[tgt[i]], 1);
        eidlist[pos] = i;
    }
}

__global__ __launch_bounds__(256) void k_amax_den(
    const float* __restrict__ alpha, const int* __restrict__ offsets,
    const int* __restrict__ eidlist, float* __restrict__ amaxF,
    float* __restrict__ invden, int NH8)
{
    int i = blockIdx.x * 256 + threadIdx.x;
    if (i >= NH8) return;
    int n = i >> 3, h = i & 7;
    int b = offsets[n], e = offsets[n + 1];
    float m = -1e30f;
    for (int k = b; k < e; ++k) m = fmaxf(m, alpha[(size_t)eidlist[k] * 8 + h]);
    float s = 0.f;
    for (int k = b; k < e; ++k) s += __expf(alpha[(size_t)eidlist[k] * 8 + h] - m);
    amaxF[i] = m;
    invden[i] = (s > 0.f) ? 1.f / s : 0.f;
}

__global__ __launch_bounds__(256) void k_norm(
    float* __restrict__ alpha, const float* __restrict__ amaxF,
    const float* __restrict__ invden, const int* __restrict__ tgt, int EH)
{
    int i = blockIdx.x * 256 + threadIdx.x;
    if (i >= EH) return;
    int e = i >> 3, h = i & 7;
    int g = tgt[e];
    alpha[i] = __expf(alpha[i] - amaxF[(size_t)g * 8 + h]) * invden[(size_t)g * 8 + h];
}

// message pass via CSR: hat[n,c] = V[n,c] * sum_{e in CSR[n]} e1[e,c]*w[e,h]
__global__ __launch_bounds__(256) void attn_msg_csr(
    const u16* __restrict__ qkv, const u16* __restrict__ e1b,
    const float* __restrict__ alpha, const int* __restrict__ offsets,
    const int* __restrict__ eidlist, float* __restrict__ hattn)
{
    int n = blockIdx.x;
    int c = threadIdx.x;
    int h = c >> 5;
    int b = offsets[n], e = offsets[n + 1];
    float acc = 0.f;
    for (int k = b; k < e; ++k) {
        int eid = eidlist[k];
        float w = alpha[(size_t)eid * 8 + h];
        acc += b2f(e1b[(size_t)eid * 256 + c]) * w;
    }
    hattn[(size_t)n * 256 + c] = b2f(qkv[(size_t)n * 768 + 512 + c]) * acc;
}

// ---------------------------------------------------------------------------------------
static inline void gemm(hipStream_t st, const u16* A, int lda, const u16* Bt, int ldb,
                        void* C, int ldc, int M, int N, int K,
                        const float* bias, int act, int obf16)
{
    dim3 g(N / 128, (M + 63) / 64);
    hipLaunchKernelGGL(gemm_mfma, g, dim3(256), 0, st, A, lda, Bt, ldb, C, ldc, M, N, K,
                       bias, act, obf16);
}

extern "C" void kernel_launch(void* const* d_in, const int* in_sizes, int n_in,
                              void* d_out, int out_size, void* d_ws, size_t ws_size,
                              hipStream_t stream)
{
    const int Nn = in_sizes[0];
    const int E = in_sizes[3] / HID;

    const float* x        = (const float*)d_in[1];
    const float* t_emb_h  = (const float*)d_in[2];
    const float* edge_attr= (const float*)d_in[3];
    const int*   eidx     = (const int*)d_in[4];
    const float* t_emb_e  = (const float*)d_in[5];
    const float* dist     = (const float*)d_in[6];
    const float* W_ee     = (const float*)d_in[7];
    const float* b_ee     = (const float*)d_in[8];
    const float* W_ad     = (const float*)d_in[9];
    const float* b_ad     = (const float*)d_in[10];
    const float* W_ade    = (const float*)d_in[11];
    const float* b_ade    = (const float*)d_in[12];
    const float* W_qkv    = (const float*)d_in[13];
    const float* W_e0     = (const float*)d_in[14];
    const float* W_e1     = (const float*)d_in[15];
    const float* W_n2e    = (const float*)d_in[16];
    const float* b_n2e    = (const float*)d_in[17];
    const float* g_ln     = (const float*)d_in[18];
    const float* b_ln     = (const float*)d_in[19];
    const float* W_f12    = (const float*)d_in[20];
    const float* W_fout   = (const float*)d_in[21];
    const float* W_fe12   = (const float*)d_in[22];
    const float* W_feout  = (const float*)d_in[23];

    const int* src = eidx;
    const int* tgt = eidx + E;

    float* outN = (float*)d_out;
    float* outE = (float*)d_out + (size_t)Nn * 256;

    // ---- persistent workspace ----
    char* W = (char*)d_ws;
    size_t off = 0;
    auto alloc = [&](size_t bytes) -> size_t {
        size_t o = off; off += (bytes + 255) & ~(size_t)255; return o;
    };
    float*    alpha = (float*)(W + alloc((size_t)E * 8 * 4));
    float*    amaxF = (float*)(W + alloc((size_t)Nn * 8 * 4));
    float*    invden= (float*)(W + alloc((size_t)Nn * 8 * 4));
    float*    hat   = (float*)(W + alloc((size_t)Nn * 256 * 4));
    int*      offs  = (int*)(W + alloc((size_t)(Nn + 1) * 4));
    int*      cursor= (int*)(W + alloc((size_t)Nn * 4));
    int*      eidl  = (int*)(W + alloc((size_t)E * 4));
    u16*      qkvb  = (u16*)(W + alloc((size_t)Nn * 768 * 2));
    u16*      sth   = (u16*)(W + alloc((size_t)Nn * 256 * 2));
    u16*      steb  = (u16*)(W + alloc((size_t)E * 256 * 2));    // silu(t_emb_e)
    u16*      eaeb  = (u16*)(W + alloc((size_t)E * 256 * 2));    // edge_attr_e (bf16)
    u16*      e1b   = (u16*)(W + alloc((size_t)E * 256 * 2));    // e_mod @ W_e1
    u16*      adnb  = (u16*)(W + alloc((size_t)Nn * 1536 * 2));
    u16*      xmb   = (u16*)(W + alloc((size_t)Nn * 256 * 2));
    u16*      h2nb  = (u16*)(W + alloc((size_t)Nn * 256 * 2));
    u16*      cnb   = (u16*)(W + alloc((size_t)Nn * 1024 * 2));
    // bf16 transposed weights (N x K)
    u16* weet   = (u16*)(W + alloc((size_t)256 * 384 * 2));
    u16* wadt   = (u16*)(W + alloc((size_t)1536 * 256 * 2));
    u16* wadet  = (u16*)(W + alloc((size_t)1536 * 256 * 2));
    u16* wqkvt  = (u16*)(W + alloc((size_t)768 * 256 * 2));
    u16* we01t  = (u16*)(W + alloc((size_t)512 * 256 * 2));
    u16* wn2et  = (u16*)(W + alloc((size_t)256 * 256 * 2));
    u16* wf12t  = (u16*)(W + alloc((size_t)2048 * 256 * 2));
    u16* wfoutt = (u16*)(W + alloc((size_t)256 * 1024 * 2));
    u16* wfe12t = (u16*)(W + alloc((size_t)2048 * 256 * 2));
    u16* wfeoutt= (u16*)(W + alloc((size_t)256 * 1024 * 2));

    char* pool = W + off;
    size_t poolB = (ws_size > off) ? (ws_size - off) : 0;
    auto chunkRowsB = [&](size_t bytesPerRow, int total) -> int {
        long c = (long)(poolB / bytesPerRow);
        c = (c / 256) * 256;
        if (c < 256) c = 256;
        if (c > total) c = (long)total;
        return (int)c;
    };

    // ---- CSR build by tgt ----
    hipMemsetAsync(cursor, 0, (size_t)Nn * 4, stream);
    hipLaunchKernelGGL(k_hist, dim3((E + 255) / 256), dim3(256), 0, stream, tgt, cursor, E);
    hipLaunchKernelGGL(k_scan, dim3(1), dim3(256), 0, stream, cursor, offs, Nn);
    hipMemcpyAsync(cursor, offs, (size_t)Nn * 4, hipMemcpyDeviceToDevice, stream);
    hipLaunchKernelGGL(k_scatter, dim3((E + 255) / 256), dim3(256), 0, stream,
                       tgt, cursor, eidl, E);

    // ---- weight conversion ----
    {
        struct WC { const float* w; u16* wt; int K, N; } wl[] = {
            { W_ee,    weet,   384, 256 },
            { W_ad,    wadt,   256, 1536 },
            { W_ade,   wadet,  256, 1536 },
            { W_qkv,   wqkvt,  256, 768 },
            { W_e0,    we01t,  256, 256 },
            { W_e1,    we01t + 256 * 256, 256, 256 },
            { W_n2e,   wn2et,  256, 256 },
            { W_f12,   wf12t,  256, 2048 },
            { W_fout,  wfoutt, 1024, 256 },
            { W_fe12,  wfe12t, 256, 2048 },
            { W_feout, wfeoutt,1024, 256 },
        };
        for (auto& e : wl) {
            int cnt = e.K * e.N;
            hipLaunchKernelGGL(k_wconv, dim3((cnt + 255) / 256), dim3(256), 0, stream,
                               e.w, e.wt, e.K, e.N);
        }
    }

    // silu conversions (persistent)
    hipLaunchKernelGGL(k_silu_b16, dim3((unsigned)(((long long)Nn * 64 + 255) / 256)), dim3(256),
                       0, stream, t_emb_h, sth, (long long)Nn * 64);
    hipLaunchKernelGGL(k_silu_b16, dim3((unsigned)(((long long)E * 64 + 255) / 256)), dim3(256),
                       0, stream, t_emb_e, steb, (long long)E * 64);

    // ---- phase 1: node pre ----
    gemm(stream, sth, 256, wadt, 256, adnb, 1536, Nn, 1536, 256, b_ad, 0, 1);
    hipLaunchKernelGGL(k_ln_mod_b16, dim3((Nn + 3) / 4), dim3(256), 0, stream,
                       x, xmb, Nn, adnb, 1536, 0, 256);
    gemm(stream, xmb, 256, wqkvt, 256, qkvb, 768, Nn, 768, 256, nullptr, 0, 1);

    // ---- phase 2: edge pre ----
    {
        int C = chunkRowsB(1024 + 512, E);
        char* p = pool;
        u16* emsb = (u16*)p; p += (size_t)C * 1024;   // adaln_e[:,0:512) (bf16)
        u16* emod = (u16*)p;                          // C x 256 bf16
        for (int s = 0; s < E; s += C) {
            int cc = (E - s < C) ? (E - s) : C;
            hipLaunchKernelGGL(gemm_cat, dim3(2, (cc + 63) / 64), dim3(256), 0, stream,
                               edge_attr + (size_t)s * 256, dist + (size_t)s * 128,
                               weet, eaeb + (size_t)s * 256, cc, b_ee);
            gemm(stream, steb + (size_t)s * 256, 256, wadet, 256, emsb, 512, cc, 512, 256,
                 b_ade, 0, 1);
            hipLaunchKernelGGL(k_ln_mod_b16src, dim3((cc + 3) / 4), dim3(256), 0, stream,
                               eaeb + (size_t)s * 256, emod, cc, emsb, 512, 0, 256);
            hipLaunchKernelGGL(gemm_e01, dim3(4, (cc + 63) / 64), dim3(256), 0, stream,
                               emod, we01t, e1b + (size_t)s * 256, cc,
                               qkvb, src + s, tgt + s, alpha + (size_t)s * 8);
        }
    }

    // ---- phase 3: softmax stats + normalize ----
    hipLaunchKernelGGL(k_amax_den, dim3((Nn * 8 + 255) / 256), dim3(256), 0, stream,
                       alpha, offs, eidl, amaxF, invden, Nn * 8);
    hipLaunchKernelGGL(k_norm, dim3((E * 8 + 255) / 256), dim3(256), 0, stream,
                       alpha, amaxF, invden, tgt, E * 8);

    // ---- phase 4: message pass via CSR ----
    hipLaunchKernelGGL(attn_msg_csr, dim3(Nn), dim3(256), 0, stream,
                       qkvb, e1b, alpha, offs, eidl, hat);

    // ---- phase 5: node finish ----
    hipLaunchKernelGGL(k_ln_mod_resid_b16, dim3((Nn + 3) / 4), dim3(256), 0, stream,
                       x, hat, h2nb, Nn, adnb, 1536, 512, adnb, 1536, 768, 1024, g_ln, b_ln);
    hipLaunchKernelGGL(gemm_ffn12, dim3(16, (Nn + 63) / 64), dim3(256), 0, stream,
                       h2nb, wf12t, cnb, Nn);
    hipLaunchKernelGGL(gemm_out_final, dim3(2, (Nn + 63) / 64), dim3(256), 0, stream,
                       cnb, wfoutt, (const u16*)nullptr, h2nb, adnb, 1536, 1280, outN, Nn);

    // ---- phase 6: edge finish ----
    {
        int C = chunkRowsB(2048 + 512 + 512 + 2048, E);
        char* p = pool;
        u16*   em2b = (u16*)p;  p += (size_t)C * 2048;   // adaln_e[:,512:1536)
        u16*   hep  = (u16*)p;  p += (size_t)C * 512;    // bf16
        u16*   h2e  = (u16*)p;  p += (size_t)C * 512;
        u16*   cne  = (u16*)p;                            // swiglu out C x 1024
        for (int s = 0; s < E; s += C) {
            int cc = (E - s < C) ? (E - s) : C;
            hipLaunchKernelGGL(gemm_gsum, dim3(2, (cc + 63) / 64), dim3(256), 0, stream,
                               hat, src + s, tgt + s, wn2et, hep, cc, b_n2e);
            gemm(stream, steb + (size_t)s * 256, 256, wadet + 512 * 256, 256, em2b, 1024,
                 cc, 1024, 256, b_ade + 512, 0, 1);
            hipLaunchKernelGGL(k_ln_mod_resid_b16bv, dim3((cc + 3) / 4), dim3(256), 0, stream,
                               edge_attr + (size_t)s * 256, hep, h2e, cc,
                               em2b, 1024, 0, em2b, 1024, 256, 512);
            hipLaunchKernelGGL(gemm_ffn12, dim3(16, (cc + 63) / 64), dim3(256), 0, stream,
                               h2e, wfe12t, cne, cc);
            hipLaunchKernelGGL(gemm_out_final, dim3(2, (cc + 63) / 64), dim3(256), 0, stream,
                               cne, wfeoutt, eaeb + (size_t)s * 256, h2e,
                               em2b, 1024, 768, outE + (size_t)s * 256, cc);
        }
    }
    (void)n_in; (void)out_size;
}